// Round 4
// baseline (731.117 us; speedup 1.0000x reference)
//
#include <hip/hip_runtime.h>
#include <hip/hip_bf16.h>

typedef __attribute__((ext_vector_type(4))) float f32x4;
typedef __attribute__((ext_vector_type(8))) short s16x8;

__device__ __forceinline__ void async_lds16(const void* g, void* l) {
  __builtin_amdgcn_global_load_lds((const __attribute__((address_space(1))) void*)g,
                                   (__attribute__((address_space(3))) void*)l, 16, 0, 0);
}

__device__ __forceinline__ short f2bf(float x) {
  __hip_bfloat16 h = __float2bfloat16(x);
  short s;
  __builtin_memcpy(&s, &h, 2);
  return s;
}

__device__ __forceinline__ s16x8 pack8(f32x4 a, f32x4 b) {
  s16x8 r;
  r[0] = f2bf(a[0]); r[1] = f2bf(a[1]); r[2] = f2bf(a[2]); r[3] = f2bf(a[3]);
  r[4] = f2bf(b[0]); r[5] = f2bf(b[1]); r[6] = f2bf(b[2]); r[7] = f2bf(b[3]);
  return r;
}

// ---------------------------------------------------------------------------
// 128x128-tile GEMM: C = act(A @ B^T [+ bias]); BK=32, 256 threads (4 waves).
// ---------------------------------------------------------------------------
template<bool RELU, bool OUT_BF16, bool HAS_BIAS>
__global__ __launch_bounds__(256) void gemm_bt(
    const __hip_bfloat16* __restrict__ Ag, const __hip_bfloat16* __restrict__ Bg,
    const float* __restrict__ biasg, void* __restrict__ Cg,
    int lda, int ldb, int K, int ldc,
    int strideA, int strideB, int strideBias, long strideC)
{
  __shared__ __align__(16) short As[4096];
  __shared__ __align__(16) short Bs[4096];
  const int tid  = threadIdx.x;
  const int lane = tid & 63;
  const int wid  = tid >> 6;
  const int z    = blockIdx.z;
  const __hip_bfloat16* A = Ag + (long)z * strideA;
  const __hip_bfloat16* B = Bg + (long)z * strideB;
  const float* bias = HAS_BIAS ? (biasg + (long)z * strideBias) : nullptr;
  const int row0 = blockIdx.y * 128;
  const int col0 = blockIdx.x * 128;

  const int srow = wid * 16 + (lane >> 2);
  const int scol = (lane & 3) * 8;

  f32x4 acc[4][4];
#pragma unroll
  for (int i = 0; i < 4; ++i)
#pragma unroll
    for (int j = 0; j < 4; ++j) acc[i][j] = (f32x4)(0.0f);

  const int rw = (wid & 1) * 64;
  const int cw = (wid >> 1) * 64;
  const int lm = lane & 15;
  const int kg = (lane >> 4) * 8;

  for (int ks = 0; ks < K; ks += 32) {
    __syncthreads();
#pragma unroll
    for (int is = 0; is < 2; ++is) {
      async_lds16(A + (long)(row0 + is * 64 + srow) * lda + ks + scol,
                  (char*)As + is * 4096 + wid * 1024);
      async_lds16(B + (long)(col0 + is * 64 + srow) * ldb + ks + scol,
                  (char*)Bs + is * 4096 + wid * 1024);
    }
    __syncthreads();
    s16x8 af[4], bf[4];
#pragma unroll
    for (int mt = 0; mt < 4; ++mt)
      af[mt] = *(const s16x8*)(As + (rw + mt * 16 + lm) * 32 + kg);
#pragma unroll
    for (int nt = 0; nt < 4; ++nt)
      bf[nt] = *(const s16x8*)(Bs + (cw + nt * 16 + lm) * 32 + kg);
#pragma unroll
    for (int mt = 0; mt < 4; ++mt)
#pragma unroll
      for (int nt = 0; nt < 4; ++nt)
        acc[mt][nt] = __builtin_amdgcn_mfma_f32_16x16x32_bf16(af[mt], bf[nt], acc[mt][nt], 0, 0, 0);
  }

  const int lr4 = (lane >> 4) * 4;
#pragma unroll
  for (int mt = 0; mt < 4; ++mt) {
#pragma unroll
    for (int nt = 0; nt < 4; ++nt) {
      const int col = col0 + cw + nt * 16 + lm;
      const float bv = HAS_BIAS ? bias[col] : 0.0f;
#pragma unroll
      for (int r = 0; r < 4; ++r) {
        const int row = row0 + rw + mt * 16 + lr4 + r;
        float v = acc[mt][nt][r] + bv;
        if (RELU) v = fmaxf(v, 0.0f);
        if (OUT_BF16)
          ((__hip_bfloat16*)Cg)[(long)z * strideC + (long)row * ldc + col] = __float2bfloat16(v);
        else
          ((float*)Cg)[(long)z * strideC + (long)row * ldc + col] = v;
      }
    }
  }
}

// ---------------------------------------------------------------------------
// 64x64-tile GEMM for the small mid-pipeline GEMMs: 4 waves in 2x2, acc 32x32
// per wave, 8 KB LDS -> deep block residency for latency overlap.
// ---------------------------------------------------------------------------
template<bool RELU, bool OUT_BF16, bool HAS_BIAS>
__global__ __launch_bounds__(256) void gemm_bt64(
    const __hip_bfloat16* __restrict__ Ag, const __hip_bfloat16* __restrict__ Bg,
    const float* __restrict__ biasg, void* __restrict__ Cg,
    int lda, int ldb, int K, int ldc,
    int strideA, int strideB, int strideBias, long strideC)
{
  __shared__ __align__(16) short As[2048];
  __shared__ __align__(16) short Bs[2048];
  const int tid  = threadIdx.x;
  const int lane = tid & 63;
  const int wid  = tid >> 6;
  const int z    = blockIdx.z;
  const __hip_bfloat16* A = Ag + (long)z * strideA;
  const __hip_bfloat16* B = Bg + (long)z * strideB;
  const float* bias = HAS_BIAS ? (biasg + (long)z * strideBias) : nullptr;
  const int row0 = blockIdx.y * 64;
  const int col0 = blockIdx.x * 64;

  const int srow = wid * 16 + (lane >> 2);
  const int scol = (lane & 3) * 8;

  f32x4 acc[2][2];
#pragma unroll
  for (int i = 0; i < 2; ++i)
#pragma unroll
    for (int j = 0; j < 2; ++j) acc[i][j] = (f32x4)(0.0f);

  const int rw = (wid & 1) * 32;
  const int cw = (wid >> 1) * 32;
  const int lm = lane & 15;
  const int kg = (lane >> 4) * 8;

  for (int ks = 0; ks < K; ks += 32) {
    __syncthreads();
    async_lds16(A + (long)(row0 + srow) * lda + ks + scol, (char*)As + wid * 1024);
    async_lds16(B + (long)(col0 + srow) * ldb + ks + scol, (char*)Bs + wid * 1024);
    __syncthreads();
    s16x8 af[2], bf[2];
#pragma unroll
    for (int mt = 0; mt < 2; ++mt)
      af[mt] = *(const s16x8*)(As + (rw + mt * 16 + lm) * 32 + kg);
#pragma unroll
    for (int nt = 0; nt < 2; ++nt)
      bf[nt] = *(const s16x8*)(Bs + (cw + nt * 16 + lm) * 32 + kg);
#pragma unroll
    for (int mt = 0; mt < 2; ++mt)
#pragma unroll
      for (int nt = 0; nt < 2; ++nt)
        acc[mt][nt] = __builtin_amdgcn_mfma_f32_16x16x32_bf16(af[mt], bf[nt], acc[mt][nt], 0, 0, 0);
  }

  const int lr4 = (lane >> 4) * 4;
#pragma unroll
  for (int mt = 0; mt < 2; ++mt) {
#pragma unroll
    for (int nt = 0; nt < 2; ++nt) {
      const int col = col0 + cw + nt * 16 + lm;
      const float bv = HAS_BIAS ? bias[col] : 0.0f;
#pragma unroll
      for (int r = 0; r < 4; ++r) {
        const int row = row0 + rw + mt * 16 + lr4 + r;
        float v = acc[mt][nt][r] + bv;
        if (RELU) v = fmaxf(v, 0.0f);
        if (OUT_BF16)
          ((__hip_bfloat16*)Cg)[(long)z * strideC + (long)row * ldc + col] = __float2bfloat16(v);
        else
          ((float*)Cg)[(long)z * strideC + (long)row * ldc + col] = v;
      }
    }
  }
}

// ---------------------------------------------------------------------------
// Split-K reduce for G1: H1 = relu(P0 + P1 + cboth) -> bf16. 4096x1024, 8-wide.
// ---------------------------------------------------------------------------
__global__ __launch_bounds__(256) void reduce_relu(
    const float* __restrict__ P, const float* __restrict__ cboth,
    __hip_bfloat16* __restrict__ H1)
{
  const int id = blockIdx.x * 256 + threadIdx.x;   // 524288 total
  const int row = id >> 7, c8 = id & 127;
  const f32x4* p0 = (const f32x4*)(P + (long)row * 1024 + c8 * 8);
  const f32x4* p1 = (const f32x4*)(P + 4194304 + (long)row * 1024 + c8 * 8);
  const f32x4* bb = (const f32x4*)(cboth + c8 * 8);
  f32x4 a = p0[0] + p1[0] + bb[0];
  f32x4 b = p0[1] + p1[1] + bb[1];
#pragma unroll
  for (int e = 0; e < 4; ++e) { a[e] = fmaxf(a[e], 0.0f); b[e] = fmaxf(b[e], 0.0f); }
  *(s16x8*)((short*)H1 + (long)row * 1024 + c8 * 8) = pack8(a, b);
}

// ---------------------------------------------------------------------------
// Fused relation head v5 (resubmit; R3 was an infra failure, no data):
//  - One block per (t,i): out tile [64 j][256 n]. 4 waves split over n
//    (64 cols each) -> zero cross-wave duplication of W2 LDS reads.
//  - H fragments formed DIRECTLY in MFMA A-fragment layout from per-lane
//    global loads (a = As[i] slice, b = Bo[j] slice); relu(a-b) packed to
//    bf16 in registers. No Hs LDS, no formation barrier.
//  - W2 chunk [256 n][64 k] bf16 (32 KB) double-buffered via global_load_lds
//    with PRE-SWIZZLED global source (linear LDS dest) + XOR ((n&7)<<4) on
//    the ds_read side -> conflict-free 128-B-stride fragment reads.
//  - a/b prefetched one chunk ahead in registers; one barrier per chunk.
//  - acc[4][4]=64 regs, ~210 total, __launch_bounds__(256,2): 2 waves/SIMD,
//    2 blocks/CU (64 KB LDS) -> latency hiding via phase diversity.
// ---------------------------------------------------------------------------
__global__ __launch_bounds__(256, 2) void rel_final(
    const float* __restrict__ AsBo, const __hip_bfloat16* __restrict__ W2b,
    const float* __restrict__ b2, float* __restrict__ out)
{
  __shared__ __align__(16) short Ws[2][16384];   // 2 x 32 KB
  const int tid  = threadIdx.x;
  const int lane = tid & 63;
  const int wid  = tid >> 6;
  // bijective XCD-chunk swizzle (4096 % 8 == 0): 8 consecutive t per XCD
  const int bid = (int)blockIdx.x;
  const int swz = (bid & 7) * 512 + (bid >> 3);
  const int t = swz >> 6;       // 0..63
  const int i = swz & 63;       // 0..63

  const float* Ap = AsBo + (long)(t * 64 + i) * 512;
  const float* Bp = AsBo + 2097152 + (long)t * 64 * 512;

  const int lm   = lane & 15;
  const int kgrp = lane >> 4;

  // staging: issue q of wave wid fills LDS rows n = wid*64 + q*8 + (lane>>3);
  // lane writes 16 B at physical byte-in-row (lane&7)*16; the pre-swizzled
  // global source supplies logical bytes ((lane&7)^(lane>>3))<<4 of that row.
  const char* w2src = (const char*)W2b
      + (long)(wid * 64 + (lane >> 3)) * 1024
      + ((((lane & 7) ^ (lane >> 3))) << 4);

  // ds_read swizzle: logical byte-in-row (kf*64 + kgrp*16) XOR ((n&7)<<4),
  // n&7 == lm&7 for our fragment rows.
  const int off0 = (kgrp * 16) ^ ((lm & 7) << 4);

  f32x4 acc[4][4];
#pragma unroll
  for (int a = 0; a < 4; ++a)
#pragma unroll
    for (int b = 0; b < 4; ++b) acc[a][b] = (f32x4)(0.0f);

  // prefetched a/b for current chunk
  f32x4 apf[2][2];        // [kf][half]
  f32x4 bpf[4][2][2];     // [mt][kf][half]
#pragma unroll
  for (int kf = 0; kf < 2; ++kf) {
    apf[kf][0] = *(const f32x4*)(Ap + kf * 32 + kgrp * 8);
    apf[kf][1] = *(const f32x4*)(Ap + kf * 32 + kgrp * 8 + 4);
  }
#pragma unroll
  for (int mt = 0; mt < 4; ++mt)
#pragma unroll
    for (int kf = 0; kf < 2; ++kf) {
      const float* br = Bp + (mt * 16 + lm) * 512 + kf * 32 + kgrp * 8;
      bpf[mt][kf][0] = *(const f32x4*)(br);
      bpf[mt][kf][1] = *(const f32x4*)(br + 4);
    }
#pragma unroll
  for (int q = 0; q < 8; ++q)
    async_lds16(w2src + q * 8192, (char*)Ws[0] + wid * 8192 + q * 1024);
  __syncthreads();

#pragma unroll
  for (int ch = 0; ch < 8; ++ch) {
    const int cur = ch & 1;
    // W2 fragments for this wave's 64 cols (8 x ds_read_b128, conflict-free)
    s16x8 bf[4][2];
#pragma unroll
    for (int nt = 0; nt < 4; ++nt)
#pragma unroll
      for (int kf = 0; kf < 2; ++kf)
        bf[nt][kf] = *(const s16x8*)((char*)Ws[cur] + wid * 8192 + nt * 2048
                                     + lm * 128 + (off0 ^ (kf * 64)));
    // form H fragments (A-operand layout) from prefetched registers
    s16x8 af[4][2];
#pragma unroll
    for (int mt = 0; mt < 4; ++mt)
#pragma unroll
      for (int kf = 0; kf < 2; ++kf) {
        f32x4 d0, d1;
#pragma unroll
        for (int e = 0; e < 4; ++e) {
          d0[e] = fmaxf(apf[kf][0][e] - bpf[mt][kf][0][e], 0.0f);
          d1[e] = fmaxf(apf[kf][1][e] - bpf[mt][kf][1][e], 0.0f);
        }
        af[mt][kf] = pack8(d0, d1);
      }
    // prefetch next chunk's a/b (same regs, WAR-safe in order) + stage next
    if (ch < 7) {
      const int ko = (ch + 1) * 64;
#pragma unroll
      for (int kf = 0; kf < 2; ++kf) {
        apf[kf][0] = *(const f32x4*)(Ap + ko + kf * 32 + kgrp * 8);
        apf[kf][1] = *(const f32x4*)(Ap + ko + kf * 32 + kgrp * 8 + 4);
      }
#pragma unroll
      for (int mt = 0; mt < 4; ++mt)
#pragma unroll
        for (int kf = 0; kf < 2; ++kf) {
          const float* br = Bp + (mt * 16 + lm) * 512 + ko + kf * 32 + kgrp * 8;
          bpf[mt][kf][0] = *(const f32x4*)(br);
          bpf[mt][kf][1] = *(const f32x4*)(br + 4);
        }
#pragma unroll
      for (int q = 0; q < 8; ++q)
        async_lds16(w2src + (ch + 1) * 128 + q * 8192,
                    (char*)Ws[cur ^ 1] + wid * 8192 + q * 1024);
    }
    __builtin_amdgcn_s_setprio(1);
#pragma unroll
    for (int mt = 0; mt < 4; ++mt)
#pragma unroll
      for (int nt = 0; nt < 4; ++nt)
#pragma unroll
        for (int kf = 0; kf < 2; ++kf)
          acc[mt][nt] = __builtin_amdgcn_mfma_f32_16x16x32_bf16(
              af[mt][kf], bf[nt][kf], acc[mt][nt], 0, 0, 0);
    __builtin_amdgcn_s_setprio(0);
    __syncthreads();
  }

  const long obase = (long)(t * 64 + i) * 16384;
#pragma unroll
  for (int mt = 0; mt < 4; ++mt) {
#pragma unroll
    for (int nt = 0; nt < 4; ++nt) {
      const int col = wid * 64 + nt * 16 + lm;
      const float bvv = b2[col];
#pragma unroll
      for (int r = 0; r < 4; ++r) {
        const int j = mt * 16 + kgrp * 4 + r;
        out[obase + j * 256 + col] = acc[mt][nt][r] + bvv;
      }
    }
  }
}

// ---------------------------------------------------------------------------
// Vectorized prep: 8-wide regions, float4 loads, s16x8 stores.
// ---------------------------------------------------------------------------
__global__ __launch_bounds__(256) void prep_kernel(
    const float* __restrict__ roi, const float* __restrict__ spatial,
    const float* __restrict__ subj_emb, const float* __restrict__ obj_emb,
    const float* __restrict__ pred_emb,
    const float* __restrict__ subj_w1, const float* __restrict__ subj_b1,
    const float* __restrict__ obj_w1, const float* __restrict__ obj_b1,
    const float* __restrict__ subj_w2, const float* __restrict__ subj_b2,
    const float* __restrict__ obj_w2, const float* __restrict__ obj_b2,
    const float* __restrict__ fs_w1, const float* __restrict__ fs_b1,
    const float* __restrict__ fs_w2, const float* __restrict__ fs_b2,
    const float* __restrict__ fo_w1, const float* __restrict__ fo_b1,
    const float* __restrict__ fo_w2, const float* __restrict__ fo_b2,
    const float* __restrict__ W_rs, const float* __restrict__ W_ro,
    const float* __restrict__ rel_w1, const float* __restrict__ rel_b1,
    const float* __restrict__ rel_w2,
    __hip_bfloat16* __restrict__ XP, __hip_bfloat16* __restrict__ W1P,
    float* __restrict__ cboth,
    __hip_bfloat16* __restrict__ Bcat2, float* __restrict__ bias2,
    __hip_bfloat16* __restrict__ WfCat, float* __restrict__ biasf,
    __hip_bfloat16* __restrict__ W4cat, float* __restrict__ bias4,
    __hip_bfloat16* __restrict__ WcCat, float* __restrict__ crel,
    __hip_bfloat16* __restrict__ W2b)
{
  int id = blockIdx.x * 256 + threadIdx.x;

  if (id < 1081344) {  // R1: XP 4096 x 2112
    int row = id / 264, c8 = id - row * 264;
    s16x8 o;
    if (c8 < 256) {
      const f32x4* src = (const f32x4*)(roi + (long)row * 2048 + c8 * 8);
      o = pack8(src[0], src[1]);
    } else {
      f32x4 a, b;
#pragma unroll
      for (int e = 0; e < 4; ++e) {
        int col = c8 * 8 + e;
        a[e] = (col < 2052) ? spatial[row * 4 + (col - 2048)] : 0.0f;
        int col2 = col + 4;
        b[e] = (col2 < 2052) ? spatial[row * 4 + (col2 - 2048)] : 0.0f;
      }
      o = pack8(a, b);
    }
    *(s16x8*)((short*)XP + (long)id * 8) = o;
    return;
  }
  id -= 1081344;
  if (id < 270336) {  // R2: W1P 1024 x 2112
    int row = id / 264, c8 = id - row * 264;
    const float* w = (row < 512) ? (subj_w1 + (long)row * 2352)
                                 : (obj_w1 + (long)(row - 512) * 2352);
    s16x8 o;
    if (c8 < 256) {
      const f32x4* src = (const f32x4*)(w + c8 * 8);
      o = pack8(src[0], src[1]);
    } else {
      f32x4 a, b;
#pragma unroll
      for (int e = 0; e < 4; ++e) {
        int col = c8 * 8 + e;
        a[e] = (col < 2052) ? w[col] : 0.0f;
        int col2 = col + 4;
        b[e] = (col2 < 2052) ? w[col2] : 0.0f;
      }
      o = pack8(a, b);
    }
    *(s16x8*)((short*)W1P + (long)id * 8) = o;
    return;
  }
  id -= 270336;
  if (id < 1024) {  // R3: cboth
    int h = id;
    const float* w; const float* e; float s;
    if (h < 512) { w = subj_w1 + (long)h * 2352 + 2052; e = subj_emb; s = subj_b1[h]; }
    else { w = obj_w1 + (long)(h - 512) * 2352 + 2052; e = obj_emb; s = obj_b1[h - 512]; }
    for (int k = 0; k < 300; ++k) s += w[k] * e[k];
    cboth[h] = s;
    return;
  }
  id -= 1024;
  if (id < 32768) {  // R4: Bcat2 copy-cast (units of 8)
    const float* src = (id < 16384) ? (subj_w2 + id * 8) : (obj_w2 + (id - 16384) * 8);
    const f32x4* s4 = (const f32x4*)src;
    *(s16x8*)((short*)Bcat2 + (long)id * 8) = pack8(s4[0], s4[1]);
    return;
  }
  id -= 32768;
  if (id < 512) { bias2[id] = (id < 256) ? subj_b2[id] : obj_b2[id - 256]; return; }
  id -= 512;
  if (id < 32768) {  // R6: WfCat = w1[:, :256] + w1[:, 256:]
    int z = id >> 14, r8 = id & 16383;
    int h = r8 >> 5, d8 = r8 & 31;
    const float* w = (z ? fo_w1 : fs_w1) + h * 512 + d8 * 8;
    const f32x4* lo = (const f32x4*)w;
    const f32x4* hi = (const f32x4*)(w + 256);
    *(s16x8*)((short*)WfCat + (long)id * 8) = pack8(lo[0] + hi[0], lo[1] + hi[1]);
    return;
  }
  id -= 32768;
  if (id < 1024) { biasf[id] = (id < 512) ? fs_b1[id] : fo_b1[id - 512]; return; }
  id -= 1024;
  if (id < 32768) {  // R8: W4cat copy-cast
    const float* src = (id < 16384) ? (fs_w2 + id * 8) : (fo_w2 + (id - 16384) * 8);
    const f32x4* s4 = (const f32x4*)src;
    *(s16x8*)((short*)W4cat + (long)id * 8) = pack8(s4[0], s4[1]);
    return;
  }
  id -= 32768;
  if (id < 512) { bias4[id] = (id < 256) ? fs_b2[id] : fo_b2[id - 256]; return; }
  id -= 512;
  if (id < 262144) {  // R10: WcCat[z][h][d] = sum_e rel_w1[h][e] * W_r{s,o}[e][d]
    int z = id >> 17, r = id & 131071;
    int h = r >> 8, d = r & 255;
    const float* Wr = z ? W_ro : W_rs;
    const float* wd = rel_w1 + (long)h * 556;
    float s = 0.0f;
    for (int e = 0; e < 256; ++e) s += wd[e] * Wr[e * 256 + d];
    WcCat[id] = __float2bfloat16(s);
    return;
  }
  id -= 262144;
  if (id < 1024) {  // R11: crel
    int z = id >> 9, h = id & 511;
    float s = 0.0f;
    if (z == 0) {
      s = rel_b1[h];
      const float* wp = rel_w1 + (long)h * 556 + 256;
      for (int k = 0; k < 300; ++k) s += pred_emb[k] * wp[k];
    }
    crel[id] = s;
    return;
  }
  id -= 1024;
  if (id < 16384) {  // R12: W2b copy-cast
    const f32x4* s4 = (const f32x4*)(rel_w2 + id * 8);
    *(s16x8*)((short*)W2b + (long)id * 8) = pack8(s4[0], s4[1]);
  }
}

extern "C" void kernel_launch(void* const* d_in, const int* in_sizes, int n_in,
                              void* d_out, int out_size, void* d_ws, size_t ws_size,
                              hipStream_t stream)
{
  const float* roi       = (const float*)d_in[0];
  const float* spatial   = (const float*)d_in[1];
  const float* subj_emb  = (const float*)d_in[3];
  const float* obj_emb   = (const float*)d_in[4];
  const float* pred_emb  = (const float*)d_in[5];
  const float* subj_w1   = (const float*)d_in[6];
  const float* subj_b1   = (const float*)d_in[7];
  const float* subj_w2   = (const float*)d_in[8];
  const float* subj_b2   = (const float*)d_in[9];
  const float* obj_w1    = (const float*)d_in[10];
  const float* obj_b1    = (const float*)d_in[11];
  const float* obj_w2    = (const float*)d_in[12];
  const float* obj_b2    = (const float*)d_in[13];
  const float* fuse_s_w1 = (const float*)d_in[14];
  const float* fuse_s_b1 = (const float*)d_in[15];
  const float* fuse_s_w2 = (const float*)d_in[16];
  const float* fuse_s_b2 = (const float*)d_in[17];
  const float* fuse_o_w1 = (const float*)d_in[18];
  const float* fuse_o_b1 = (const float*)d_in[19];
  const float* fuse_o_w2 = (const float*)d_in[20];
  const float* fuse_o_b2 = (const float*)d_in[21];
  const float* W_rs      = (const float*)d_in[22];
  const float* W_ro      = (const float*)d_in[23];
  const float* rel_w1    = (const float*)d_in[24];
  const float* rel_b1    = (const float*)d_in[25];
  const float* rel_w2    = (const float*)d_in[26];
  const float* rel_b2    = (const float*)d_in[27];

  char* ws = (char*)d_ws;
  // XP: 4096x2112 bf16 = 17,301,504 B ; later reused as AsBo (16,777,216 B fp32)
  __hip_bfloat16* XP   = (__hip_bfloat16*)(ws);
  float*          AsBo = (float*)(ws);
  __hip_bfloat16* W1P  = (__hip_bfloat16*)(ws + 17301504);   // 1024x2112 bf16 = 4,325,376
  __hip_bfloat16* H1   = (__hip_bfloat16*)(ws + 21626880);   // 4096x1024 bf16 = 8,388,608
  __hip_bfloat16* FS   = (__hip_bfloat16*)(ws + 30015488);   // 4096x512  bf16 = 4,194,304
  float*          P    = (float*)(ws + 34209792);            // 2x4096x1024 fp32 = 33,554,432
  const size_t so = 67764224;
  __hip_bfloat16* Bcat2 = (__hip_bfloat16*)(ws + so);
  float*          bias2 = (float*)(ws + so + 524288);
  __hip_bfloat16* WfCat = (__hip_bfloat16*)(ws + so + 526336);
  float*          biasf = (float*)(ws + so + 1050624);
  __hip_bfloat16* W4cat = (__hip_bfloat16*)(ws + so + 1054720);
  float*          bias4 = (float*)(ws + so + 1579008);
  __hip_bfloat16* WcCat = (__hip_bfloat16*)(ws + so + 1581056);
  float*          crel  = (float*)(ws + so + 2105344);
  __hip_bfloat16* W2b   = (__hip_bfloat16*)(ws + so + 2109440);
  float*          cboth = (float*)(ws + so + 2371584);
  // total ws use ~70.2 MB

  prep_kernel<<<6768, 256, 0, stream>>>(
      roi, spatial, subj_emb, obj_emb, pred_emb,
      subj_w1, subj_b1, obj_w1, obj_b1, subj_w2, subj_b2, obj_w2, obj_b2,
      fuse_s_w1, fuse_s_b1, fuse_s_w2, fuse_s_b2,
      fuse_o_w1, fuse_o_b1, fuse_o_w2, fuse_o_b2,
      W_rs, W_ro, rel_w1, rel_b1, rel_w2,
      XP, W1P, cboth, Bcat2, bias2, WfCat, biasf, W4cat, bias4, WcCat, crel, W2b);

  // G1 split-K=2: P[z] = XP[:, z*1056:(z+1)*1056] @ W1P[:, same]^T  (fp32, no bias)
  gemm_bt<false, false, false><<<dim3(8, 32, 2), 256, 0, stream>>>(
      XP, W1P, cboth, P, 2112, 2112, 1056, 1024, 1056, 1056, 0, 4194304L);
  // reduce: H1 = relu(P0 + P1 + cboth) -> bf16
  reduce_relu<<<2048, 256, 0, stream>>>(P, cboth, H1);
  // G2: FS[:, z*256:] = H1[:, z*512:] @ w2_z^T + b2_z   K=512
  gemm_bt64<false, true, true><<<dim3(4, 64, 2), 256, 0, stream>>>(
      H1, Bcat2, bias2, FS, 1024, 512, 512, 512, 512, 131072, 256, 256);
  // G3: G[:, z*512:] = relu(FS[:, z*256:] @ Wf_z^T + bf_z)   K=256 (G in H1 slot)
  gemm_bt64<true, true, true><<<dim3(8, 64, 2), 256, 0, stream>>>(
      FS, WfCat, biasf, H1, 512, 256, 256, 1024, 256, 131072, 512, 512);
  // G4: Ffin[:, z*256:] = G[:, z*512:] @ w4_z^T + b4_z   K=512 (Ffin in FS slot)
  gemm_bt64<false, true, true><<<dim3(4, 64, 2), 256, 0, stream>>>(
      H1, W4cat, bias4, FS, 1024, 512, 512, 512, 512, 131072, 256, 256);
  // G5: AsBo[z] = Ffin[:, z*256:] @ Wc_z^T + crel_z  (fp32 out)  K=256
  gemm_bt64<false, false, true><<<dim3(8, 64, 2), 256, 0, stream>>>(
      FS, WcCat, crel, AsBo, 512, 256, 256, 512, 256, 131072, 512, 2097152L);
  // Fused relation head v5: register-H, 1 block per (t,i), XCD-swizzled
  rel_final<<<4096, 256, 0, stream>>>(AsBo, W2b, rel_b2, (float*)d_out);
}

// Round 5
// 553.391 us; speedup vs baseline: 1.3212x; 1.3212x over previous
//
#include <hip/hip_runtime.h>
#include <hip/hip_bf16.h>

typedef __attribute__((ext_vector_type(4))) float f32x4;
typedef __attribute__((ext_vector_type(8))) short s16x8;

__device__ __forceinline__ void async_lds16(const void* g, void* l) {
  __builtin_amdgcn_global_load_lds((const __attribute__((address_space(1))) void*)g,
                                   (__attribute__((address_space(3))) void*)l, 16, 0, 0);
}

__device__ __forceinline__ short f2bf(float x) {
  __hip_bfloat16 h = __float2bfloat16(x);
  short s;
  __builtin_memcpy(&s, &h, 2);
  return s;
}

__device__ __forceinline__ s16x8 pack8(f32x4 a, f32x4 b) {
  s16x8 r;
  r[0] = f2bf(a[0]); r[1] = f2bf(a[1]); r[2] = f2bf(a[2]); r[3] = f2bf(a[3]);
  r[4] = f2bf(b[0]); r[5] = f2bf(b[1]); r[6] = f2bf(b[2]); r[7] = f2bf(b[3]);
  return r;
}

// ---------------------------------------------------------------------------
// 128x128-tile GEMM: C = act(A @ B^T [+ bias]); BK=32, 256 threads (4 waves).
// ---------------------------------------------------------------------------
template<bool RELU, bool OUT_BF16, bool HAS_BIAS>
__global__ __launch_bounds__(256) void gemm_bt(
    const __hip_bfloat16* __restrict__ Ag, const __hip_bfloat16* __restrict__ Bg,
    const float* __restrict__ biasg, void* __restrict__ Cg,
    int lda, int ldb, int K, int ldc,
    int strideA, int strideB, int strideBias, long strideC)
{
  __shared__ __align__(16) short As[4096];
  __shared__ __align__(16) short Bs[4096];
  const int tid  = threadIdx.x;
  const int lane = tid & 63;
  const int wid  = tid >> 6;
  const int z    = blockIdx.z;
  const __hip_bfloat16* A = Ag + (long)z * strideA;
  const __hip_bfloat16* B = Bg + (long)z * strideB;
  const float* bias = HAS_BIAS ? (biasg + (long)z * strideBias) : nullptr;
  const int row0 = blockIdx.y * 128;
  const int col0 = blockIdx.x * 128;

  const int srow = wid * 16 + (lane >> 2);
  const int scol = (lane & 3) * 8;

  f32x4 acc[4][4];
#pragma unroll
  for (int i = 0; i < 4; ++i)
#pragma unroll
    for (int j = 0; j < 4; ++j) acc[i][j] = (f32x4)(0.0f);

  const int rw = (wid & 1) * 64;
  const int cw = (wid >> 1) * 64;
  const int lm = lane & 15;
  const int kg = (lane >> 4) * 8;

  for (int ks = 0; ks < K; ks += 32) {
    __syncthreads();
#pragma unroll
    for (int is = 0; is < 2; ++is) {
      async_lds16(A + (long)(row0 + is * 64 + srow) * lda + ks + scol,
                  (char*)As + is * 4096 + wid * 1024);
      async_lds16(B + (long)(col0 + is * 64 + srow) * ldb + ks + scol,
                  (char*)Bs + is * 4096 + wid * 1024);
    }
    __syncthreads();
    s16x8 af[4], bf[4];
#pragma unroll
    for (int mt = 0; mt < 4; ++mt)
      af[mt] = *(const s16x8*)(As + (rw + mt * 16 + lm) * 32 + kg);
#pragma unroll
    for (int nt = 0; nt < 4; ++nt)
      bf[nt] = *(const s16x8*)(Bs + (cw + nt * 16 + lm) * 32 + kg);
#pragma unroll
    for (int mt = 0; mt < 4; ++mt)
#pragma unroll
      for (int nt = 0; nt < 4; ++nt)
        acc[mt][nt] = __builtin_amdgcn_mfma_f32_16x16x32_bf16(af[mt], bf[nt], acc[mt][nt], 0, 0, 0);
  }

  const int lr4 = (lane >> 4) * 4;
#pragma unroll
  for (int mt = 0; mt < 4; ++mt) {
#pragma unroll
    for (int nt = 0; nt < 4; ++nt) {
      const int col = col0 + cw + nt * 16 + lm;
      const float bv = HAS_BIAS ? bias[col] : 0.0f;
#pragma unroll
      for (int r = 0; r < 4; ++r) {
        const int row = row0 + rw + mt * 16 + lr4 + r;
        float v = acc[mt][nt][r] + bv;
        if (RELU) v = fmaxf(v, 0.0f);
        if (OUT_BF16)
          ((__hip_bfloat16*)Cg)[(long)z * strideC + (long)row * ldc + col] = __float2bfloat16(v);
        else
          ((float*)Cg)[(long)z * strideC + (long)row * ldc + col] = v;
      }
    }
  }
}

// ---------------------------------------------------------------------------
// 64x64-tile GEMM for the small mid-pipeline GEMMs: 4 waves in 2x2, acc 32x32
// per wave, 8 KB LDS -> deep block residency for latency overlap.
// ---------------------------------------------------------------------------
template<bool RELU, bool OUT_BF16, bool HAS_BIAS>
__global__ __launch_bounds__(256) void gemm_bt64(
    const __hip_bfloat16* __restrict__ Ag, const __hip_bfloat16* __restrict__ Bg,
    const float* __restrict__ biasg, void* __restrict__ Cg,
    int lda, int ldb, int K, int ldc,
    int strideA, int strideB, int strideBias, long strideC)
{
  __shared__ __align__(16) short As[2048];
  __shared__ __align__(16) short Bs[2048];
  const int tid  = threadIdx.x;
  const int lane = tid & 63;
  const int wid  = tid >> 6;
  const int z    = blockIdx.z;
  const __hip_bfloat16* A = Ag + (long)z * strideA;
  const __hip_bfloat16* B = Bg + (long)z * strideB;
  const float* bias = HAS_BIAS ? (biasg + (long)z * strideBias) : nullptr;
  const int row0 = blockIdx.y * 64;
  const int col0 = blockIdx.x * 64;

  const int srow = wid * 16 + (lane >> 2);
  const int scol = (lane & 3) * 8;

  f32x4 acc[2][2];
#pragma unroll
  for (int i = 0; i < 2; ++i)
#pragma unroll
    for (int j = 0; j < 2; ++j) acc[i][j] = (f32x4)(0.0f);

  const int rw = (wid & 1) * 32;
  const int cw = (wid >> 1) * 32;
  const int lm = lane & 15;
  const int kg = (lane >> 4) * 8;

  for (int ks = 0; ks < K; ks += 32) {
    __syncthreads();
    async_lds16(A + (long)(row0 + srow) * lda + ks + scol, (char*)As + wid * 1024);
    async_lds16(B + (long)(col0 + srow) * ldb + ks + scol, (char*)Bs + wid * 1024);
    __syncthreads();
    s16x8 af[2], bf[2];
#pragma unroll
    for (int mt = 0; mt < 2; ++mt)
      af[mt] = *(const s16x8*)(As + (rw + mt * 16 + lm) * 32 + kg);
#pragma unroll
    for (int nt = 0; nt < 2; ++nt)
      bf[nt] = *(const s16x8*)(Bs + (cw + nt * 16 + lm) * 32 + kg);
#pragma unroll
    for (int mt = 0; mt < 2; ++mt)
#pragma unroll
      for (int nt = 0; nt < 2; ++nt)
        acc[mt][nt] = __builtin_amdgcn_mfma_f32_16x16x32_bf16(af[mt], bf[nt], acc[mt][nt], 0, 0, 0);
  }

  const int lr4 = (lane >> 4) * 4;
#pragma unroll
  for (int mt = 0; mt < 2; ++mt) {
#pragma unroll
    for (int nt = 0; nt < 2; ++nt) {
      const int col = col0 + cw + nt * 16 + lm;
      const float bv = HAS_BIAS ? bias[col] : 0.0f;
#pragma unroll
      for (int r = 0; r < 4; ++r) {
        const int row = row0 + rw + mt * 16 + lr4 + r;
        float v = acc[mt][nt][r] + bv;
        if (RELU) v = fmaxf(v, 0.0f);
        if (OUT_BF16)
          ((__hip_bfloat16*)Cg)[(long)z * strideC + (long)row * ldc + col] = __float2bfloat16(v);
        else
          ((float*)Cg)[(long)z * strideC + (long)row * ldc + col] = v;
      }
    }
  }
}

// ---------------------------------------------------------------------------
// Split-K reduce for G1: H1 = relu(P0 + P1 + cboth) -> bf16. 4096x1024, 8-wide.
// ---------------------------------------------------------------------------
__global__ __launch_bounds__(256) void reduce_relu(
    const float* __restrict__ P, const float* __restrict__ cboth,
    __hip_bfloat16* __restrict__ H1)
{
  const int id = blockIdx.x * 256 + threadIdx.x;   // 524288 total
  const int row = id >> 7, c8 = id & 127;
  const f32x4* p0 = (const f32x4*)(P + (long)row * 1024 + c8 * 8);
  const f32x4* p1 = (const f32x4*)(P + 4194304 + (long)row * 1024 + c8 * 8);
  const f32x4* bb = (const f32x4*)(cboth + c8 * 8);
  f32x4 a = p0[0] + p1[0] + bb[0];
  f32x4 b = p0[1] + p1[1] + bb[1];
#pragma unroll
  for (int e = 0; e < 4; ++e) { a[e] = fmaxf(a[e], 0.0f); b[e] = fmaxf(b[e], 0.0f); }
  *(s16x8*)((short*)H1 + (long)row * 1024 + c8 * 8) = pack8(a, b);
}

// ---------------------------------------------------------------------------
// Fused relation head v6: cooperative LDS-H formation (fixes v5's L1-request
// bound), register-free fragment sourcing for B via coalesced rows.
//  - v5's fatal flaw: per-lane b-frag global loads strided 2 KB across lanes
//    -> ~64 line-requests per load inst -> ~167M requests (matches 327 us).
//  - v6: per chunk, 256 threads form H (64j x 64k bf16, 8 KB) cooperatively:
//    thread (j=tid>>2, ks=tid&3) reads Bp[j] as 4 CONSECUTIVE f32x4 (256 B
//    contiguous per row -> coalesced), a-row broadcast; relu(a-b) -> bf16 ->
//    XOR-swizzled LDS. All 4 waves then ds_read identical A-frags (8x b128,
//    conflict-free via the same (slot ^ row&7) involution verified in v5).
//  - Ws staging + fragment reads + epilogue: v5-verified code, unchanged.
//  - LDS 80 KB (2x32 Ws + 2x8 Hs) -> 2 blocks/CU; acc[4][4]; one barrier
//    per chunk; global loads for chunk ch+1 issued before MFMA of chunk ch.
// ---------------------------------------------------------------------------
__global__ __launch_bounds__(256, 2) void rel_final(
    const float* __restrict__ AsBo, const __hip_bfloat16* __restrict__ W2b,
    const float* __restrict__ b2, float* __restrict__ out)
{
  __shared__ __align__(16) short Ws[2][16384];   // 2 x 32 KB
  __shared__ __align__(16) short Hs[2][4096];    // 2 x 8 KB, swizzled
  const int tid  = threadIdx.x;
  const int lane = tid & 63;
  const int wid  = tid >> 6;
  // bijective XCD-chunk swizzle (4096 % 8 == 0): 8 consecutive t per XCD
  const int bid = (int)blockIdx.x;
  const int swz = (bid & 7) * 512 + (bid >> 3);
  const int t = swz >> 6;       // 0..63
  const int i = swz & 63;       // 0..63

  const float* Ap = AsBo + (long)(t * 64 + i) * 512;
  const float* Bp = AsBo + 2097152 + (long)t * 64 * 512;

  const int lm   = lane & 15;
  const int kgrp = lane >> 4;

  // formation mapping: thread -> (row fj 0..63, 16-wide k-slice fks 0..3)
  const int fj  = tid >> 2;
  const int fks = tid & 3;
  const float* fb = Bp + fj * 512 + fks * 16;   // + ch*64 + q*4
  const float* fa = Ap + fks * 16;
  // swizzled H write byte offsets (two 16B stores per thread per chunk)
  const int hw0 = fj * 128 + (((fks * 2)     ^ (fj & 7)) << 4);
  const int hw1 = fj * 128 + (((fks * 2 + 1) ^ (fj & 7)) << 4);

  // Ws staging (v5-verified): pre-swizzled global source, linear LDS dest
  const char* w2src = (const char*)W2b
      + (long)(wid * 64 + (lane >> 3)) * 1024
      + ((((lane & 7) ^ (lane >> 3))) << 4);

  f32x4 acc[4][4];
#pragma unroll
  for (int a = 0; a < 4; ++a)
#pragma unroll
    for (int b = 0; b < 4; ++b) acc[a][b] = (f32x4)(0.0f);

  // ---- prologue: chunk 0 -> buffer 0
  {
#pragma unroll
    for (int q = 0; q < 8; ++q)
      async_lds16(w2src + q * 8192, (char*)Ws[0] + wid * 8192 + q * 1024);
    f32x4 d0, d1, d2, d3;
    {
      f32x4 b0 = *(const f32x4*)(fb);
      f32x4 b1 = *(const f32x4*)(fb + 4);
      f32x4 b2v = *(const f32x4*)(fb + 8);
      f32x4 b3 = *(const f32x4*)(fb + 12);
      f32x4 a0 = *(const f32x4*)(fa);
      f32x4 a1 = *(const f32x4*)(fa + 4);
      f32x4 a2 = *(const f32x4*)(fa + 8);
      f32x4 a3 = *(const f32x4*)(fa + 12);
#pragma unroll
      for (int e = 0; e < 4; ++e) {
        d0[e] = fmaxf(a0[e] - b0[e], 0.0f);
        d1[e] = fmaxf(a1[e] - b1[e], 0.0f);
        d2[e] = fmaxf(a2[e] - b2v[e], 0.0f);
        d3[e] = fmaxf(a3[e] - b3[e], 0.0f);
      }
    }
    *(s16x8*)((char*)Hs[0] + hw0) = pack8(d0, d1);
    *(s16x8*)((char*)Hs[0] + hw1) = pack8(d2, d3);
  }
  __syncthreads();

#pragma unroll
  for (int ch = 0; ch < 8; ++ch) {
    const int cur = ch & 1;
    // fragment reads from current buffers (conflict-free, swizzled)
    s16x8 af[4][2], bf[4][2];
#pragma unroll
    for (int kf = 0; kf < 2; ++kf) {
      const int hs = (((kf * 4 + kgrp) ^ (lm & 7)) << 4);
#pragma unroll
      for (int mt = 0; mt < 4; ++mt)
        af[mt][kf] = *(const s16x8*)((char*)Hs[cur] + (mt * 16 + lm) * 128 + hs);
#pragma unroll
      for (int nt = 0; nt < 4; ++nt)
        bf[nt][kf] = *(const s16x8*)((char*)Ws[cur] + wid * 8192 + nt * 2048
                                     + lm * 128 + hs);
    }
    // issue next chunk's global work before MFMA (latency hides under compute)
    f32x4 av[4], bv[4];
    if (ch < 7) {
      const int ko = (ch + 1) * 64;
#pragma unroll
      for (int q = 0; q < 4; ++q) {
        bv[q] = *(const f32x4*)(fb + ko + q * 4);
        av[q] = *(const f32x4*)(fa + ko + q * 4);
      }
#pragma unroll
      for (int q = 0; q < 8; ++q)
        async_lds16(w2src + (ch + 1) * 128 + q * 8192,
                    (char*)Ws[cur ^ 1] + wid * 8192 + q * 1024);
    }
    __builtin_amdgcn_s_setprio(1);
#pragma unroll
    for (int mt = 0; mt < 4; ++mt)
#pragma unroll
      for (int nt = 0; nt < 4; ++nt)
#pragma unroll
        for (int kf = 0; kf < 2; ++kf)
          acc[mt][nt] = __builtin_amdgcn_mfma_f32_16x16x32_bf16(
              af[mt][kf], bf[nt][kf], acc[mt][nt], 0, 0, 0);
    __builtin_amdgcn_s_setprio(0);
    if (ch < 7) {
      f32x4 d0, d1, d2, d3;
#pragma unroll
      for (int e = 0; e < 4; ++e) {
        d0[e] = fmaxf(av[0][e] - bv[0][e], 0.0f);
        d1[e] = fmaxf(av[1][e] - bv[1][e], 0.0f);
        d2[e] = fmaxf(av[2][e] - bv[2][e], 0.0f);
        d3[e] = fmaxf(av[3][e] - bv[3][e], 0.0f);
      }
      *(s16x8*)((char*)Hs[cur ^ 1] + hw0) = pack8(d0, d1);
      *(s16x8*)((char*)Hs[cur ^ 1] + hw1) = pack8(d2, d3);
    }
    __syncthreads();
  }

  const long obase = (long)(t * 64 + i) * 16384;
#pragma unroll
  for (int mt = 0; mt < 4; ++mt) {
#pragma unroll
    for (int nt = 0; nt < 4; ++nt) {
      const int col = wid * 64 + nt * 16 + lm;
      const float bvv = b2[col];
#pragma unroll
      for (int r = 0; r < 4; ++r) {
        const int j = mt * 16 + kgrp * 4 + r;
        out[obase + j * 256 + col] = acc[mt][nt][r] + bvv;
      }
    }
  }
}

// ---------------------------------------------------------------------------
// Vectorized prep: 8-wide regions, float4 loads, s16x8 stores.
// ---------------------------------------------------------------------------
__global__ __launch_bounds__(256) void prep_kernel(
    const float* __restrict__ roi, const float* __restrict__ spatial,
    const float* __restrict__ subj_emb, const float* __restrict__ obj_emb,
    const float* __restrict__ pred_emb,
    const float* __restrict__ subj_w1, const float* __restrict__ subj_b1,
    const float* __restrict__ obj_w1, const float* __restrict__ obj_b1,
    const float* __restrict__ subj_w2, const float* __restrict__ subj_b2,
    const float* __restrict__ obj_w2, const float* __restrict__ obj_b2,
    const float* __restrict__ fs_w1, const float* __restrict__ fs_b1,
    const float* __restrict__ fs_w2, const float* __restrict__ fs_b2,
    const float* __restrict__ fo_w1, const float* __restrict__ fo_b1,
    const float* __restrict__ fo_w2, const float* __restrict__ fo_b2,
    const float* __restrict__ W_rs, const float* __restrict__ W_ro,
    const float* __restrict__ rel_w1, const float* __restrict__ rel_b1,
    const float* __restrict__ rel_w2,
    __hip_bfloat16* __restrict__ XP, __hip_bfloat16* __restrict__ W1P,
    float* __restrict__ cboth,
    __hip_bfloat16* __restrict__ Bcat2, float* __restrict__ bias2,
    __hip_bfloat16* __restrict__ WfCat, float* __restrict__ biasf,
    __hip_bfloat16* __restrict__ W4cat, float* __restrict__ bias4,
    __hip_bfloat16* __restrict__ WcCat, float* __restrict__ crel,
    __hip_bfloat16* __restrict__ W2b)
{
  int id = blockIdx.x * 256 + threadIdx.x;

  if (id < 1081344) {  // R1: XP 4096 x 2112
    int row = id / 264, c8 = id - row * 264;
    s16x8 o;
    if (c8 < 256) {
      const f32x4* src = (const f32x4*)(roi + (long)row * 2048 + c8 * 8);
      o = pack8(src[0], src[1]);
    } else {
      f32x4 a, b;
#pragma unroll
      for (int e = 0; e < 4; ++e) {
        int col = c8 * 8 + e;
        a[e] = (col < 2052) ? spatial[row * 4 + (col - 2048)] : 0.0f;
        int col2 = col + 4;
        b[e] = (col2 < 2052) ? spatial[row * 4 + (col2 - 2048)] : 0.0f;
      }
      o = pack8(a, b);
    }
    *(s16x8*)((short*)XP + (long)id * 8) = o;
    return;
  }
  id -= 1081344;
  if (id < 270336) {  // R2: W1P 1024 x 2112
    int row = id / 264, c8 = id - row * 264;
    const float* w = (row < 512) ? (subj_w1 + (long)row * 2352)
                                 : (obj_w1 + (long)(row - 512) * 2352);
    s16x8 o;
    if (c8 < 256) {
      const f32x4* src = (const f32x4*)(w + c8 * 8);
      o = pack8(src[0], src[1]);
    } else {
      f32x4 a, b;
#pragma unroll
      for (int e = 0; e < 4; ++e) {
        int col = c8 * 8 + e;
        a[e] = (col < 2052) ? w[col] : 0.0f;
        int col2 = col + 4;
        b[e] = (col2 < 2052) ? w[col2] : 0.0f;
      }
      o = pack8(a, b);
    }
    *(s16x8*)((short*)W1P + (long)id * 8) = o;
    return;
  }
  id -= 270336;
  if (id < 1024) {  // R3: cboth
    int h = id;
    const float* w; const float* e; float s;
    if (h < 512) { w = subj_w1 + (long)h * 2352 + 2052; e = subj_emb; s = subj_b1[h]; }
    else { w = obj_w1 + (long)(h - 512) * 2352 + 2052; e = obj_emb; s = obj_b1[h - 512]; }
    for (int k = 0; k < 300; ++k) s += w[k] * e[k];
    cboth[h] = s;
    return;
  }
  id -= 1024;
  if (id < 32768) {  // R4: Bcat2 copy-cast (units of 8)
    const float* src = (id < 16384) ? (subj_w2 + id * 8) : (obj_w2 + (id - 16384) * 8);
    const f32x4* s4 = (const f32x4*)src;
    *(s16x8*)((short*)Bcat2 + (long)id * 8) = pack8(s4[0], s4[1]);
    return;
  }
  id -= 32768;
  if (id < 512) { bias2[id] = (id < 256) ? subj_b2[id] : obj_b2[id - 256]; return; }
  id -= 512;
  if (id < 32768) {  // R6: WfCat = w1[:, :256] + w1[:, 256:]
    int z = id >> 14, r8 = id & 16383;
    int h = r8 >> 5, d8 = r8 & 31;
    const float* w = (z ? fo_w1 : fs_w1) + h * 512 + d8 * 8;
    const f32x4* lo = (const f32x4*)w;
    const f32x4* hi = (const f32x4*)(w + 256);
    *(s16x8*)((short*)WfCat + (long)id * 8) = pack8(lo[0] + hi[0], lo[1] + hi[1]);
    return;
  }
  id -= 32768;
  if (id < 1024) { biasf[id] = (id < 512) ? fs_b1[id] : fo_b1[id - 512]; return; }
  id -= 1024;
  if (id < 32768) {  // R8: W4cat copy-cast
    const float* src = (id < 16384) ? (fs_w2 + id * 8) : (fo_w2 + (id - 16384) * 8);
    const f32x4* s4 = (const f32x4*)src;
    *(s16x8*)((short*)W4cat + (long)id * 8) = pack8(s4[0], s4[1]);
    return;
  }
  id -= 32768;
  if (id < 512) { bias4[id] = (id < 256) ? fs_b2[id] : fo_b2[id - 256]; return; }
  id -= 512;
  if (id < 262144) {  // R10: WcCat[z][h][d] = sum_e rel_w1[h][e] * W_r{s,o}[e][d]
    int z = id >> 17, r = id & 131071;
    int h = r >> 8, d = r & 255;
    const float* Wr = z ? W_ro : W_rs;
    const float* wd = rel_w1 + (long)h * 556;
    float s = 0.0f;
    for (int e = 0; e < 256; ++e) s += wd[e] * Wr[e * 256 + d];
    WcCat[id] = __float2bfloat16(s);
    return;
  }
  id -= 262144;
  if (id < 1024) {  // R11: crel
    int z = id >> 9, h = id & 511;
    float s = 0.0f;
    if (z == 0) {
      s = rel_b1[h];
      const float* wp = rel_w1 + (long)h * 556 + 256;
      for (int k = 0; k < 300; ++k) s += pred_emb[k] * wp[k];
    }
    crel[id] = s;
    return;
  }
  id -= 1024;
  if (id < 16384) {  // R12: W2b copy-cast
    const f32x4* s4 = (const f32x4*)(rel_w2 + id * 8);
    *(s16x8*)((short*)W2b + (long)id * 8) = pack8(s4[0], s4[1]);
  }
}

extern "C" void kernel_launch(void* const* d_in, const int* in_sizes, int n_in,
                              void* d_out, int out_size, void* d_ws, size_t ws_size,
                              hipStream_t stream)
{
  const float* roi       = (const float*)d_in[0];
  const float* spatial   = (const float*)d_in[1];
  const float* subj_emb  = (const float*)d_in[3];
  const float* obj_emb   = (const float*)d_in[4];
  const float* pred_emb  = (const float*)d_in[5];
  const float* subj_w1   = (const float*)d_in[6];
  const float* subj_b1   = (const float*)d_in[7];
  const float* subj_w2   = (const float*)d_in[8];
  const float* subj_b2   = (const float*)d_in[9];
  const float* obj_w1    = (const float*)d_in[10];
  const float* obj_b1    = (const float*)d_in[11];
  const float* obj_w2    = (const float*)d_in[12];
  const float* obj_b2    = (const float*)d_in[13];
  const float* fuse_s_w1 = (const float*)d_in[14];
  const float* fuse_s_b1 = (const float*)d_in[15];
  const float* fuse_s_w2 = (const float*)d_in[16];
  const float* fuse_s_b2 = (const float*)d_in[17];
  const float* fuse_o_w1 = (const float*)d_in[18];
  const float* fuse_o_b1 = (const float*)d_in[19];
  const float* fuse_o_w2 = (const float*)d_in[20];
  const float* fuse_o_b2 = (const float*)d_in[21];
  const float* W_rs      = (const float*)d_in[22];
  const float* W_ro      = (const float*)d_in[23];
  const float* rel_w1    = (const float*)d_in[24];
  const float* rel_b1    = (const float*)d_in[25];
  const float* rel_w2    = (const float*)d_in[26];
  const float* rel_b2    = (const float*)d_in[27];

  char* ws = (char*)d_ws;
  // XP: 4096x2112 bf16 = 17,301,504 B ; later reused as AsBo (16,777,216 B fp32)
  __hip_bfloat16* XP   = (__hip_bfloat16*)(ws);
  float*          AsBo = (float*)(ws);
  __hip_bfloat16* W1P  = (__hip_bfloat16*)(ws + 17301504);   // 1024x2112 bf16 = 4,325,376
  __hip_bfloat16* H1   = (__hip_bfloat16*)(ws + 21626880);   // 4096x1024 bf16 = 8,388,608
  __hip_bfloat16* FS   = (__hip_bfloat16*)(ws + 30015488);   // 4096x512  bf16 = 4,194,304
  float*          P    = (float*)(ws + 34209792);            // 2x4096x1024 fp32 = 33,554,432
  const size_t so = 67764224;
  __hip_bfloat16* Bcat2 = (__hip_bfloat16*)(ws + so);
  float*          bias2 = (float*)(ws + so + 524288);
  __hip_bfloat16* WfCat = (__hip_bfloat16*)(ws + so + 526336);
  float*          biasf = (float*)(ws + so + 1050624);
  __hip_bfloat16* W4cat = (__hip_bfloat16*)(ws + so + 1054720);
  float*          bias4 = (float*)(ws + so + 1579008);
  __hip_bfloat16* WcCat = (__hip_bfloat16*)(ws + so + 1581056);
  float*          crel  = (float*)(ws + so + 2105344);
  __hip_bfloat16* W2b   = (__hip_bfloat16*)(ws + so + 2109440);
  float*          cboth = (float*)(ws + so + 2371584);
  // total ws use ~70.2 MB

  prep_kernel<<<6768, 256, 0, stream>>>(
      roi, spatial, subj_emb, obj_emb, pred_emb,
      subj_w1, subj_b1, obj_w1, obj_b1, subj_w2, subj_b2, obj_w2, obj_b2,
      fuse_s_w1, fuse_s_b1, fuse_s_w2, fuse_s_b2,
      fuse_o_w1, fuse_o_b1, fuse_o_w2, fuse_o_b2,
      W_rs, W_ro, rel_w1, rel_b1, rel_w2,
      XP, W1P, cboth, Bcat2, bias2, WfCat, biasf, W4cat, bias4, WcCat, crel, W2b);

  // G1 split-K=2: P[z] = XP[:, z*1056:(z+1)*1056] @ W1P[:, same]^T  (fp32, no bias)
  gemm_bt<false, false, false><<<dim3(8, 32, 2), 256, 0, stream>>>(
      XP, W1P, cboth, P, 2112, 2112, 1056, 1024, 1056, 1056, 0, 4194304L);
  // reduce: H1 = relu(P0 + P1 + cboth) -> bf16
  reduce_relu<<<2048, 256, 0, stream>>>(P, cboth, H1);
  // G2: FS[:, z*256:] = H1[:, z*512:] @ w2_z^T + b2_z   K=512
  gemm_bt64<false, true, true><<<dim3(4, 64, 2), 256, 0, stream>>>(
      H1, Bcat2, bias2, FS, 1024, 512, 512, 512, 512, 131072, 256, 256);
  // G3: G[:, z*512:] = relu(FS[:, z*256:] @ Wf_z^T + bf_z)   K=256 (G in H1 slot)
  gemm_bt64<true, true, true><<<dim3(8, 64, 2), 256, 0, stream>>>(
      FS, WfCat, biasf, H1, 512, 256, 256, 1024, 256, 131072, 512, 512);
  // G4: Ffin[:, z*256:] = G[:, z*512:] @ w4_z^T + b4_z   K=512 (Ffin in FS slot)
  gemm_bt64<false, true, true><<<dim3(4, 64, 2), 256, 0, stream>>>(
      H1, W4cat, bias4, FS, 1024, 512, 512, 512, 512, 131072, 256, 256);
  // G5: AsBo[z] = Ffin[:, z*256:] @ Wc_z^T + crel_z  (fp32 out)  K=256
  gemm_bt64<false, false, true><<<dim3(8, 64, 2), 256, 0, stream>>>(
      FS, WcCat, crel, AsBo, 512, 256, 256, 512, 256, 131072, 512, 2097152L);
  // Fused relation head v6: cooperative LDS-H formation, coalesced loads
  rel_final<<<4096, 256, 0, stream>>>(AsBo, W2b, rel_b2, (float*)d_out);
}

// Round 6
// 529.578 us; speedup vs baseline: 1.3806x; 1.0450x over previous
//
#include <hip/hip_runtime.h>
#include <hip/hip_bf16.h>

typedef __attribute__((ext_vector_type(4))) float f32x4;
typedef __attribute__((ext_vector_type(8))) short s16x8;

__device__ __forceinline__ void async_lds16(const void* g, void* l) {
  __builtin_amdgcn_global_load_lds((const __attribute__((address_space(1))) void*)g,
                                   (__attribute__((address_space(3))) void*)l, 16, 0, 0);
}

__device__ __forceinline__ short f2bf(float x) {
  __hip_bfloat16 h = __float2bfloat16(x);
  short s;
  __builtin_memcpy(&s, &h, 2);
  return s;
}

__device__ __forceinline__ s16x8 pack8(f32x4 a, f32x4 b) {
  s16x8 r;
  r[0] = f2bf(a[0]); r[1] = f2bf(a[1]); r[2] = f2bf(a[2]); r[3] = f2bf(a[3]);
  r[4] = f2bf(b[0]); r[5] = f2bf(b[1]); r[6] = f2bf(b[2]); r[7] = f2bf(b[3]);
  return r;
}

// ---------------------------------------------------------------------------
// 128x128-tile GEMM: C = act(A @ B^T [+ bias]); BK=32, 256 threads (4 waves).
// ---------------------------------------------------------------------------
template<bool RELU, bool OUT_BF16, bool HAS_BIAS>
__global__ __launch_bounds__(256) void gemm_bt(
    const __hip_bfloat16* __restrict__ Ag, const __hip_bfloat16* __restrict__ Bg,
    const float* __restrict__ biasg, void* __restrict__ Cg,
    int lda, int ldb, int K, int ldc,
    int strideA, int strideB, int strideBias, long strideC)
{
  __shared__ __align__(16) short As[4096];
  __shared__ __align__(16) short Bs[4096];
  const int tid  = threadIdx.x;
  const int lane = tid & 63;
  const int wid  = tid >> 6;
  const int z    = blockIdx.z;
  const __hip_bfloat16* A = Ag + (long)z * strideA;
  const __hip_bfloat16* B = Bg + (long)z * strideB;
  const float* bias = HAS_BIAS ? (biasg + (long)z * strideBias) : nullptr;
  const int row0 = blockIdx.y * 128;
  const int col0 = blockIdx.x * 128;

  const int srow = wid * 16 + (lane >> 2);
  const int scol = (lane & 3) * 8;

  f32x4 acc[4][4];
#pragma unroll
  for (int i = 0; i < 4; ++i)
#pragma unroll
    for (int j = 0; j < 4; ++j) acc[i][j] = (f32x4)(0.0f);

  const int rw = (wid & 1) * 64;
  const int cw = (wid >> 1) * 64;
  const int lm = lane & 15;
  const int kg = (lane >> 4) * 8;

  for (int ks = 0; ks < K; ks += 32) {
    __syncthreads();
#pragma unroll
    for (int is = 0; is < 2; ++is) {
      async_lds16(A + (long)(row0 + is * 64 + srow) * lda + ks + scol,
                  (char*)As + is * 4096 + wid * 1024);
      async_lds16(B + (long)(col0 + is * 64 + srow) * ldb + ks + scol,
                  (char*)Bs + is * 4096 + wid * 1024);
    }
    __syncthreads();
    s16x8 af[4], bf[4];
#pragma unroll
    for (int mt = 0; mt < 4; ++mt)
      af[mt] = *(const s16x8*)(As + (rw + mt * 16 + lm) * 32 + kg);
#pragma unroll
    for (int nt = 0; nt < 4; ++nt)
      bf[nt] = *(const s16x8*)(Bs + (cw + nt * 16 + lm) * 32 + kg);
#pragma unroll
    for (int mt = 0; mt < 4; ++mt)
#pragma unroll
      for (int nt = 0; nt < 4; ++nt)
        acc[mt][nt] = __builtin_amdgcn_mfma_f32_16x16x32_bf16(af[mt], bf[nt], acc[mt][nt], 0, 0, 0);
  }

  const int lr4 = (lane >> 4) * 4;
#pragma unroll
  for (int mt = 0; mt < 4; ++mt) {
#pragma unroll
    for (int nt = 0; nt < 4; ++nt) {
      const int col = col0 + cw + nt * 16 + lm;
      const float bv = HAS_BIAS ? bias[col] : 0.0f;
#pragma unroll
      for (int r = 0; r < 4; ++r) {
        const int row = row0 + rw + mt * 16 + lr4 + r;
        float v = acc[mt][nt][r] + bv;
        if (RELU) v = fmaxf(v, 0.0f);
        if (OUT_BF16)
          ((__hip_bfloat16*)Cg)[(long)z * strideC + (long)row * ldc + col] = __float2bfloat16(v);
        else
          ((float*)Cg)[(long)z * strideC + (long)row * ldc + col] = v;
      }
    }
  }
}

// ---------------------------------------------------------------------------
// 64x64-tile GEMM for the small mid-pipeline GEMMs: 4 waves in 2x2, acc 32x32
// per wave, 8 KB LDS -> deep block residency for latency overlap.
// ---------------------------------------------------------------------------
template<bool RELU, bool OUT_BF16, bool HAS_BIAS>
__global__ __launch_bounds__(256) void gemm_bt64(
    const __hip_bfloat16* __restrict__ Ag, const __hip_bfloat16* __restrict__ Bg,
    const float* __restrict__ biasg, void* __restrict__ Cg,
    int lda, int ldb, int K, int ldc,
    int strideA, int strideB, int strideBias, long strideC)
{
  __shared__ __align__(16) short As[2048];
  __shared__ __align__(16) short Bs[2048];
  const int tid  = threadIdx.x;
  const int lane = tid & 63;
  const int wid  = tid >> 6;
  const int z    = blockIdx.z;
  const __hip_bfloat16* A = Ag + (long)z * strideA;
  const __hip_bfloat16* B = Bg + (long)z * strideB;
  const float* bias = HAS_BIAS ? (biasg + (long)z * strideBias) : nullptr;
  const int row0 = blockIdx.y * 64;
  const int col0 = blockIdx.x * 64;

  const int srow = wid * 16 + (lane >> 2);
  const int scol = (lane & 3) * 8;

  f32x4 acc[2][2];
#pragma unroll
  for (int i = 0; i < 2; ++i)
#pragma unroll
    for (int j = 0; j < 2; ++j) acc[i][j] = (f32x4)(0.0f);

  const int rw = (wid & 1) * 32;
  const int cw = (wid >> 1) * 32;
  const int lm = lane & 15;
  const int kg = (lane >> 4) * 8;

  for (int ks = 0; ks < K; ks += 32) {
    __syncthreads();
    async_lds16(A + (long)(row0 + srow) * lda + ks + scol, (char*)As + wid * 1024);
    async_lds16(B + (long)(col0 + srow) * ldb + ks + scol, (char*)Bs + wid * 1024);
    __syncthreads();
    s16x8 af[2], bf[2];
#pragma unroll
    for (int mt = 0; mt < 2; ++mt)
      af[mt] = *(const s16x8*)(As + (rw + mt * 16 + lm) * 32 + kg);
#pragma unroll
    for (int nt = 0; nt < 2; ++nt)
      bf[nt] = *(const s16x8*)(Bs + (cw + nt * 16 + lm) * 32 + kg);
#pragma unroll
    for (int mt = 0; mt < 2; ++mt)
#pragma unroll
      for (int nt = 0; nt < 2; ++nt)
        acc[mt][nt] = __builtin_amdgcn_mfma_f32_16x16x32_bf16(af[mt], bf[nt], acc[mt][nt], 0, 0, 0);
  }

  const int lr4 = (lane >> 4) * 4;
#pragma unroll
  for (int mt = 0; mt < 2; ++mt) {
#pragma unroll
    for (int nt = 0; nt < 2; ++nt) {
      const int col = col0 + cw + nt * 16 + lm;
      const float bv = HAS_BIAS ? bias[col] : 0.0f;
#pragma unroll
      for (int r = 0; r < 4; ++r) {
        const int row = row0 + rw + mt * 16 + lr4 + r;
        float v = acc[mt][nt][r] + bv;
        if (RELU) v = fmaxf(v, 0.0f);
        if (OUT_BF16)
          ((__hip_bfloat16*)Cg)[(long)z * strideC + (long)row * ldc + col] = __float2bfloat16(v);
        else
          ((float*)Cg)[(long)z * strideC + (long)row * ldc + col] = v;
      }
    }
  }
}

// ---------------------------------------------------------------------------
// Split-K reduce for G1: H1 = relu(P0 + P1 + cboth) -> bf16. 4096x1024, 8-wide.
// ---------------------------------------------------------------------------
__global__ __launch_bounds__(256) void reduce_relu(
    const float* __restrict__ P, const float* __restrict__ cboth,
    __hip_bfloat16* __restrict__ H1)
{
  const int id = blockIdx.x * 256 + threadIdx.x;   // 524288 total
  const int row = id >> 7, c8 = id & 127;
  const f32x4* p0 = (const f32x4*)(P + (long)row * 1024 + c8 * 8);
  const f32x4* p1 = (const f32x4*)(P + 4194304 + (long)row * 1024 + c8 * 8);
  const f32x4* bb = (const f32x4*)(cboth + c8 * 8);
  f32x4 a = p0[0] + p1[0] + bb[0];
  f32x4 b = p0[1] + p1[1] + bb[1];
#pragma unroll
  for (int e = 0; e < 4; ++e) { a[e] = fmaxf(a[e], 0.0f); b[e] = fmaxf(b[e], 0.0f); }
  *(s16x8*)((short*)H1 + (long)row * 1024 + c8 * 8) = pack8(a, b);
}

// ---------------------------------------------------------------------------
// Fused relation head v7: v6 structure with K-chunk halved to 32.
//  - LDS 40 KB (2x16 Ws + 2x4 Hs) -> 4 blocks/CU (16 waves) vs v6's 2:
//    doubles the latency-hiding pool for the per-chunk stage->drain gap.
//  - 64 B rows (4 x 16B slots); bank swizzle: physical slot = logical ^
//    ((row>>1)&3) -> exactly 2 lanes/bank-slot on fragment reads (free).
//    Staging source pre-swizzled with the same involution (linear LDS dest);
//    H-formation ds_writes apply it directly.
//  - Per chunk: 16 MFMA/wave; stage (4 async_lds16/wave) + next a/b loads
//    issued before MFMA; one barrier per chunk (16 total).
//  - __launch_bounds__(256,4): VGPR cap 128 (v6 compiled at 128 with more
//    live state; v7 has fewer fragments live).
// ---------------------------------------------------------------------------
__global__ __launch_bounds__(256, 4) void rel_final(
    const float* __restrict__ AsBo, const __hip_bfloat16* __restrict__ W2b,
    const float* __restrict__ b2, float* __restrict__ out)
{
  __shared__ __align__(16) short Ws[2][8192];   // 2 x 16 KB: [256 n][32 k]
  __shared__ __align__(16) short Hs[2][2048];   // 2 x 4 KB:  [64 j][32 k]
  const int tid  = threadIdx.x;
  const int lane = tid & 63;
  const int wid  = tid >> 6;
  // bijective XCD-chunk swizzle (4096 % 8 == 0): 8 consecutive t per XCD
  const int bid = (int)blockIdx.x;
  const int swz = (bid & 7) * 512 + (bid >> 3);
  const int t = swz >> 6;       // 0..63
  const int i = swz & 63;       // 0..63

  const float* Ap = AsBo + (long)(t * 64 + i) * 512;
  const float* Bp = AsBo + 2097152 + (long)t * 64 * 512;

  const int lm   = lane & 15;
  const int kgrp = lane >> 4;

  // formation mapping: thread -> (row fj 0..63, 8-wide k-slice fks 0..3)
  const int fj  = tid >> 2;
  const int fks = tid & 3;
  const float* fb = Bp + fj * 512 + fks * 8;
  const float* fa = Ap + fks * 8;
  // swizzled H write byte offset: physical slot = fks ^ ((fj>>1)&3)
  const int hw = fj * 64 + ((fks ^ ((fj >> 1) & 3)) << 4);

  // Ws staging: issue q fills rows wid*64 + q*16 + (lane>>2); lane writes
  // 16 B at physical slot lane&3; source supplies logical slot
  // (lane&3) ^ ((row>>1)&3) = (lane&3) ^ ((lane>>3)&3).
  const char* w2src = (const char*)W2b
      + (long)(wid * 64 + (lane >> 2)) * 1024
      + ((((lane & 3) ^ ((lane >> 3) & 3))) << 4);

  // fragment read slot (rows mt*16+lm / wid*64+nt*16+lm both have
  // (row>>1)&3 == (lm>>1)&3): physical slot = kgrp ^ ((lm>>1)&3)
  const int fslot = (kgrp ^ ((lm >> 1) & 3)) << 4;

  f32x4 acc[4][4];
#pragma unroll
  for (int a = 0; a < 4; ++a)
#pragma unroll
    for (int b = 0; b < 4; ++b) acc[a][b] = (f32x4)(0.0f);

  // ---- prologue: chunk 0 -> buffer 0
  {
#pragma unroll
    for (int q = 0; q < 4; ++q)
      async_lds16(w2src + q * 16384, (char*)Ws[0] + wid * 4096 + q * 1024);
    f32x4 b0 = *(const f32x4*)(fb);
    f32x4 b1 = *(const f32x4*)(fb + 4);
    f32x4 a0 = *(const f32x4*)(fa);
    f32x4 a1 = *(const f32x4*)(fa + 4);
    f32x4 d0, d1;
#pragma unroll
    for (int e = 0; e < 4; ++e) {
      d0[e] = fmaxf(a0[e] - b0[e], 0.0f);
      d1[e] = fmaxf(a1[e] - b1[e], 0.0f);
    }
    *(s16x8*)((char*)Hs[0] + hw) = pack8(d0, d1);
  }
  __syncthreads();

#pragma unroll
  for (int ch = 0; ch < 16; ++ch) {
    const int cur = ch & 1;
    // fragment reads from current buffers (2-way bank aliasing = free)
    s16x8 af[4], bf[4];
#pragma unroll
    for (int mt = 0; mt < 4; ++mt)
      af[mt] = *(const s16x8*)((char*)Hs[cur] + (mt * 16 + lm) * 64 + fslot);
#pragma unroll
    for (int nt = 0; nt < 4; ++nt)
      bf[nt] = *(const s16x8*)((char*)Ws[cur] + wid * 4096 + nt * 1024
                               + lm * 64 + fslot);
    // issue next chunk's global work before MFMA (latency hides under compute)
    f32x4 av0, av1, bv0, bv1;
    if (ch < 15) {
      const int ko = (ch + 1) * 32;
      bv0 = *(const f32x4*)(fb + ko);
      bv1 = *(const f32x4*)(fb + ko + 4);
      av0 = *(const f32x4*)(fa + ko);
      av1 = *(const f32x4*)(fa + ko + 4);
#pragma unroll
      for (int q = 0; q < 4; ++q)
        async_lds16(w2src + (ch + 1) * 64 + q * 16384,
                    (char*)Ws[cur ^ 1] + wid * 4096 + q * 1024);
    }
    __builtin_amdgcn_s_setprio(1);
#pragma unroll
    for (int mt = 0; mt < 4; ++mt)
#pragma unroll
      for (int nt = 0; nt < 4; ++nt)
        acc[mt][nt] = __builtin_amdgcn_mfma_f32_16x16x32_bf16(
            af[mt], bf[nt], acc[mt][nt], 0, 0, 0);
    __builtin_amdgcn_s_setprio(0);
    if (ch < 15) {
      f32x4 d0, d1;
#pragma unroll
      for (int e = 0; e < 4; ++e) {
        d0[e] = fmaxf(av0[e] - bv0[e], 0.0f);
        d1[e] = fmaxf(av1[e] - bv1[e], 0.0f);
      }
      *(s16x8*)((char*)Hs[cur ^ 1] + hw) = pack8(d0, d1);
    }
    __syncthreads();
  }

  const long obase = (long)(t * 64 + i) * 16384;
#pragma unroll
  for (int mt = 0; mt < 4; ++mt) {
#pragma unroll
    for (int nt = 0; nt < 4; ++nt) {
      const int col = wid * 64 + nt * 16 + lm;
      const float bvv = b2[col];
#pragma unroll
      for (int r = 0; r < 4; ++r) {
        const int j = mt * 16 + kgrp * 4 + r;
        out[obase + j * 256 + col] = acc[mt][nt][r] + bvv;
      }
    }
  }
}

// ---------------------------------------------------------------------------
// Vectorized prep: 8-wide regions, float4 loads, s16x8 stores.
// ---------------------------------------------------------------------------
__global__ __launch_bounds__(256) void prep_kernel(
    const float* __restrict__ roi, const float* __restrict__ spatial,
    const float* __restrict__ subj_emb, const float* __restrict__ obj_emb,
    const float* __restrict__ pred_emb,
    const float* __restrict__ subj_w1, const float* __restrict__ subj_b1,
    const float* __restrict__ obj_w1, const float* __restrict__ obj_b1,
    const float* __restrict__ subj_w2, const float* __restrict__ subj_b2,
    const float* __restrict__ obj_w2, const float* __restrict__ obj_b2,
    const float* __restrict__ fs_w1, const float* __restrict__ fs_b1,
    const float* __restrict__ fs_w2, const float* __restrict__ fs_b2,
    const float* __restrict__ fo_w1, const float* __restrict__ fo_b1,
    const float* __restrict__ fo_w2, const float* __restrict__ fo_b2,
    const float* __restrict__ W_rs, const float* __restrict__ W_ro,
    const float* __restrict__ rel_w1, const float* __restrict__ rel_b1,
    const float* __restrict__ rel_w2,
    __hip_bfloat16* __restrict__ XP, __hip_bfloat16* __restrict__ W1P,
    float* __restrict__ cboth,
    __hip_bfloat16* __restrict__ Bcat2, float* __restrict__ bias2,
    __hip_bfloat16* __restrict__ WfCat, float* __restrict__ biasf,
    __hip_bfloat16* __restrict__ W4cat, float* __restrict__ bias4,
    __hip_bfloat16* __restrict__ WcCat, float* __restrict__ crel,
    __hip_bfloat16* __restrict__ W2b)
{
  int id = blockIdx.x * 256 + threadIdx.x;

  if (id < 1081344) {  // R1: XP 4096 x 2112
    int row = id / 264, c8 = id - row * 264;
    s16x8 o;
    if (c8 < 256) {
      const f32x4* src = (const f32x4*)(roi + (long)row * 2048 + c8 * 8);
      o = pack8(src[0], src[1]);
    } else {
      f32x4 a, b;
#pragma unroll
      for (int e = 0; e < 4; ++e) {
        int col = c8 * 8 + e;
        a[e] = (col < 2052) ? spatial[row * 4 + (col - 2048)] : 0.0f;
        int col2 = col + 4;
        b[e] = (col2 < 2052) ? spatial[row * 4 + (col2 - 2048)] : 0.0f;
      }
      o = pack8(a, b);
    }
    *(s16x8*)((short*)XP + (long)id * 8) = o;
    return;
  }
  id -= 1081344;
  if (id < 270336) {  // R2: W1P 1024 x 2112
    int row = id / 264, c8 = id - row * 264;
    const float* w = (row < 512) ? (subj_w1 + (long)row * 2352)
                                 : (obj_w1 + (long)(row - 512) * 2352);
    s16x8 o;
    if (c8 < 256) {
      const f32x4* src = (const f32x4*)(w + c8 * 8);
      o = pack8(src[0], src[1]);
    } else {
      f32x4 a, b;
#pragma unroll
      for (int e = 0; e < 4; ++e) {
        int col = c8 * 8 + e;
        a[e] = (col < 2052) ? w[col] : 0.0f;
        int col2 = col + 4;
        b[e] = (col2 < 2052) ? w[col2] : 0.0f;
      }
      o = pack8(a, b);
    }
    *(s16x8*)((short*)W1P + (long)id * 8) = o;
    return;
  }
  id -= 270336;
  if (id < 1024) {  // R3: cboth
    int h = id;
    const float* w; const float* e; float s;
    if (h < 512) { w = subj_w1 + (long)h * 2352 + 2052; e = subj_emb; s = subj_b1[h]; }
    else { w = obj_w1 + (long)(h - 512) * 2352 + 2052; e = obj_emb; s = obj_b1[h - 512]; }
    for (int k = 0; k < 300; ++k) s += w[k] * e[k];
    cboth[h] = s;
    return;
  }
  id -= 1024;
  if (id < 32768) {  // R4: Bcat2 copy-cast (units of 8)
    const float* src = (id < 16384) ? (subj_w2 + id * 8) : (obj_w2 + (id - 16384) * 8);
    const f32x4* s4 = (const f32x4*)src;
    *(s16x8*)((short*)Bcat2 + (long)id * 8) = pack8(s4[0], s4[1]);
    return;
  }
  id -= 32768;
  if (id < 512) { bias2[id] = (id < 256) ? subj_b2[id] : obj_b2[id - 256]; return; }
  id -= 512;
  if (id < 32768) {  // R6: WfCat = w1[:, :256] + w1[:, 256:]
    int z = id >> 14, r8 = id & 16383;
    int h = r8 >> 5, d8 = r8 & 31;
    const float* w = (z ? fo_w1 : fs_w1) + h * 512 + d8 * 8;
    const f32x4* lo = (const f32x4*)w;
    const f32x4* hi = (const f32x4*)(w + 256);
    *(s16x8*)((short*)WfCat + (long)id * 8) = pack8(lo[0] + hi[0], lo[1] + hi[1]);
    return;
  }
  id -= 32768;
  if (id < 1024) { biasf[id] = (id < 512) ? fs_b1[id] : fo_b1[id - 512]; return; }
  id -= 1024;
  if (id < 32768) {  // R8: W4cat copy-cast
    const float* src = (id < 16384) ? (fs_w2 + id * 8) : (fo_w2 + (id - 16384) * 8);
    const f32x4* s4 = (const f32x4*)src;
    *(s16x8*)((short*)W4cat + (long)id * 8) = pack8(s4[0], s4[1]);
    return;
  }
  id -= 32768;
  if (id < 512) { bias4[id] = (id < 256) ? fs_b2[id] : fo_b2[id - 256]; return; }
  id -= 512;
  if (id < 262144) {  // R10: WcCat[z][h][d] = sum_e rel_w1[h][e] * W_r{s,o}[e][d]
    int z = id >> 17, r = id & 131071;
    int h = r >> 8, d = r & 255;
    const float* Wr = z ? W_ro : W_rs;
    const float* wd = rel_w1 + (long)h * 556;
    float s = 0.0f;
    for (int e = 0; e < 256; ++e) s += wd[e] * Wr[e * 256 + d];
    WcCat[id] = __float2bfloat16(s);
    return;
  }
  id -= 262144;
  if (id < 1024) {  // R11: crel
    int z = id >> 9, h = id & 511;
    float s = 0.0f;
    if (z == 0) {
      s = rel_b1[h];
      const float* wp = rel_w1 + (long)h * 556 + 256;
      for (int k = 0; k < 300; ++k) s += pred_emb[k] * wp[k];
    }
    crel[id] = s;
    return;
  }
  id -= 1024;
  if (id < 16384) {  // R12: W2b copy-cast
    const f32x4* s4 = (const f32x4*)(rel_w2 + id * 8);
    *(s16x8*)((short*)W2b + (long)id * 8) = pack8(s4[0], s4[1]);
  }
}

extern "C" void kernel_launch(void* const* d_in, const int* in_sizes, int n_in,
                              void* d_out, int out_size, void* d_ws, size_t ws_size,
                              hipStream_t stream)
{
  const float* roi       = (const float*)d_in[0];
  const float* spatial   = (const float*)d_in[1];
  const float* subj_emb  = (const float*)d_in[3];
  const float* obj_emb   = (const float*)d_in[4];
  const float* pred_emb  = (const float*)d_in[5];
  const float* subj_w1   = (const float*)d_in[6];
  const float* subj_b1   = (const float*)d_in[7];
  const float* subj_w2   = (const float*)d_in[8];
  const float* subj_b2   = (const float*)d_in[9];
  const float* obj_w1    = (const float*)d_in[10];
  const float* obj_b1    = (const float*)d_in[11];
  const float* obj_w2    = (const float*)d_in[12];
  const float* obj_b2    = (const float*)d_in[13];
  const float* fuse_s_w1 = (const float*)d_in[14];
  const float* fuse_s_b1 = (const float*)d_in[15];
  const float* fuse_s_w2 = (const float*)d_in[16];
  const float* fuse_s_b2 = (const float*)d_in[17];
  const float* fuse_o_w1 = (const float*)d_in[18];
  const float* fuse_o_b1 = (const float*)d_in[19];
  const float* fuse_o_w2 = (const float*)d_in[20];
  const float* fuse_o_b2 = (const float*)d_in[21];
  const float* W_rs      = (const float*)d_in[22];
  const float* W_ro      = (const float*)d_in[23];
  const float* rel_w1    = (const float*)d_in[24];
  const float* rel_b1    = (const float*)d_in[25];
  const float* rel_w2    = (const float*)d_in[26];
  const float* rel_b2    = (const float*)d_in[27];

  char* ws = (char*)d_ws;
  // XP: 4096x2112 bf16 = 17,301,504 B ; later reused as AsBo (16,777,216 B fp32)
  __hip_bfloat16* XP   = (__hip_bfloat16*)(ws);
  float*          AsBo = (float*)(ws);
  __hip_bfloat16* W1P  = (__hip_bfloat16*)(ws + 17301504);   // 1024x2112 bf16 = 4,325,376
  __hip_bfloat16* H1   = (__hip_bfloat16*)(ws + 21626880);   // 4096x1024 bf16 = 8,388,608
  __hip_bfloat16* FS   = (__hip_bfloat16*)(ws + 30015488);   // 4096x512  bf16 = 4,194,304
  float*          P    = (float*)(ws + 34209792);            // 2x4096x1024 fp32 = 33,554,432
  const size_t so = 67764224;
  __hip_bfloat16* Bcat2 = (__hip_bfloat16*)(ws + so);
  float*          bias2 = (float*)(ws + so + 524288);
  __hip_bfloat16* WfCat = (__hip_bfloat16*)(ws + so + 526336);
  float*          biasf = (float*)(ws + so + 1050624);
  __hip_bfloat16* W4cat = (__hip_bfloat16*)(ws + so + 1054720);
  float*          bias4 = (float*)(ws + so + 1579008);
  __hip_bfloat16* WcCat = (__hip_bfloat16*)(ws + so + 1581056);
  float*          crel  = (float*)(ws + so + 2105344);
  __hip_bfloat16* W2b   = (__hip_bfloat16*)(ws + so + 2109440);
  float*          cboth = (float*)(ws + so + 2371584);
  // total ws use ~70.2 MB

  prep_kernel<<<6768, 256, 0, stream>>>(
      roi, spatial, subj_emb, obj_emb, pred_emb,
      subj_w1, subj_b1, obj_w1, obj_b1, subj_w2, subj_b2, obj_w2, obj_b2,
      fuse_s_w1, fuse_s_b1, fuse_s_w2, fuse_s_b2,
      fuse_o_w1, fuse_o_b1, fuse_o_w2, fuse_o_b2,
      W_rs, W_ro, rel_w1, rel_b1, rel_w2,
      XP, W1P, cboth, Bcat2, bias2, WfCat, biasf, W4cat, bias4, WcCat, crel, W2b);

  // G1 split-K=2: P[z] = XP[:, z*1056:(z+1)*1056] @ W1P[:, same]^T  (fp32, no bias)
  gemm_bt<false, false, false><<<dim3(8, 32, 2), 256, 0, stream>>>(
      XP, W1P, cboth, P, 2112, 2112, 1056, 1024, 1056, 1056, 0, 4194304L);
  // reduce: H1 = relu(P0 + P1 + cboth) -> bf16
  reduce_relu<<<2048, 256, 0, stream>>>(P, cboth, H1);
  // G2: FS[:, z*256:] = H1[:, z*512:] @ w2_z^T + b2_z   K=512
  gemm_bt64<false, true, true><<<dim3(4, 64, 2), 256, 0, stream>>>(
      H1, Bcat2, bias2, FS, 1024, 512, 512, 512, 512, 131072, 256, 256);
  // G3: G[:, z*512:] = relu(FS[:, z*256:] @ Wf_z^T + bf_z)   K=256 (G in H1 slot)
  gemm_bt64<true, true, true><<<dim3(8, 64, 2), 256, 0, stream>>>(
      FS, WfCat, biasf, H1, 512, 256, 256, 1024, 256, 131072, 512, 512);
  // G4: Ffin[:, z*256:] = G[:, z*512:] @ w4_z^T + b4_z   K=512 (Ffin in FS slot)
  gemm_bt64<false, true, true><<<dim3(4, 64, 2), 256, 0, stream>>>(
      H1, W4cat, bias4, FS, 1024, 512, 512, 512, 512, 131072, 256, 256);
  // G5: AsBo[z] = Ffin[:, z*256:] @ Wc_z^T + crel_z  (fp32 out)  K=256
  gemm_bt64<false, false, true><<<dim3(8, 64, 2), 256, 0, stream>>>(
      FS, WcCat, crel, AsBo, 512, 256, 256, 512, 256, 131072, 512, 2097152L);
  // Fused relation head v7: K=32 chunks, 4 blocks/CU
  rel_final<<<4096, 256, 0, stream>>>(AsBo, W2b, rel_b2, (float*)d_out);
}

// Round 8
// 528.179 us; speedup vs baseline: 1.3842x; 1.0026x over previous
//
#include <hip/hip_runtime.h>
#include <hip/hip_bf16.h>

typedef __attribute__((ext_vector_type(4))) float f32x4;
typedef __attribute__((ext_vector_type(8))) short s16x8;

__device__ __forceinline__ void async_lds16(const void* g, void* l) {
  __builtin_amdgcn_global_load_lds((const __attribute__((address_space(1))) void*)g,
                                   (__attribute__((address_space(3))) void*)l, 16, 0, 0);
}

__device__ __forceinline__ short f2bf(float x) {
  __hip_bfloat16 h = __float2bfloat16(x);
  short s;
  __builtin_memcpy(&s, &h, 2);
  return s;
}

__device__ __forceinline__ s16x8 pack8(f32x4 a, f32x4 b) {
  s16x8 r;
  r[0] = f2bf(a[0]); r[1] = f2bf(a[1]); r[2] = f2bf(a[2]); r[3] = f2bf(a[3]);
  r[4] = f2bf(b[0]); r[5] = f2bf(b[1]); r[6] = f2bf(b[2]); r[7] = f2bf(b[3]);
  return r;
}

// ---------------------------------------------------------------------------
// 128x128-tile GEMM v2: double-buffered, ONE barrier per k-step (v7 pattern).
// Per k-step: stage k+1 -> ds_read k -> MFMA (prio 1) -> barrier.
// ---------------------------------------------------------------------------
template<bool RELU, bool OUT_BF16, bool HAS_BIAS>
__global__ __launch_bounds__(256) void gemm_bt(
    const __hip_bfloat16* __restrict__ Ag, const __hip_bfloat16* __restrict__ Bg,
    const float* __restrict__ biasg, void* __restrict__ Cg,
    int lda, int ldb, int K, int ldc,
    int strideA, int strideB, int strideBias, long strideC)
{
  __shared__ __align__(16) short As[2][4096];
  __shared__ __align__(16) short Bs[2][4096];
  const int tid  = threadIdx.x;
  const int lane = tid & 63;
  const int wid  = tid >> 6;
  const int z    = blockIdx.z;
  const __hip_bfloat16* A = Ag + (long)z * strideA;
  const __hip_bfloat16* B = Bg + (long)z * strideB;
  const float* bias = HAS_BIAS ? (biasg + (long)z * strideBias) : nullptr;
  const int row0 = blockIdx.y * 128;
  const int col0 = blockIdx.x * 128;

  const int srow = wid * 16 + (lane >> 2);
  const int scol = (lane & 3) * 8;

  f32x4 acc[4][4];
#pragma unroll
  for (int i = 0; i < 4; ++i)
#pragma unroll
    for (int j = 0; j < 4; ++j) acc[i][j] = (f32x4)(0.0f);

  const int rw = (wid & 1) * 64;
  const int cw = (wid >> 1) * 64;
  const int lm = lane & 15;
  const int kg = (lane >> 4) * 8;
  const int nk = K >> 5;

  // prologue: k-step 0 -> buffer 0
#pragma unroll
  for (int is = 0; is < 2; ++is) {
    async_lds16(A + (long)(row0 + is * 64 + srow) * lda + scol,
                (char*)As[0] + is * 4096 + wid * 1024);
    async_lds16(B + (long)(col0 + is * 64 + srow) * ldb + scol,
                (char*)Bs[0] + is * 4096 + wid * 1024);
  }
  __syncthreads();

  for (int it = 0; it < nk; ++it) {
    const int cur = it & 1;
    if (it + 1 < nk) {
      const int ksn = (it + 1) << 5;
#pragma unroll
      for (int is = 0; is < 2; ++is) {
        async_lds16(A + (long)(row0 + is * 64 + srow) * lda + ksn + scol,
                    (char*)As[cur ^ 1] + is * 4096 + wid * 1024);
        async_lds16(B + (long)(col0 + is * 64 + srow) * ldb + ksn + scol,
                    (char*)Bs[cur ^ 1] + is * 4096 + wid * 1024);
      }
    }
    s16x8 af[4], bf[4];
#pragma unroll
    for (int mt = 0; mt < 4; ++mt)
      af[mt] = *(const s16x8*)(As[cur] + (rw + mt * 16 + lm) * 32 + kg);
#pragma unroll
    for (int nt = 0; nt < 4; ++nt)
      bf[nt] = *(const s16x8*)(Bs[cur] + (cw + nt * 16 + lm) * 32 + kg);
    __builtin_amdgcn_s_setprio(1);
#pragma unroll
    for (int mt = 0; mt < 4; ++mt)
#pragma unroll
      for (int nt = 0; nt < 4; ++nt)
        acc[mt][nt] = __builtin_amdgcn_mfma_f32_16x16x32_bf16(af[mt], bf[nt], acc[mt][nt], 0, 0, 0);
    __builtin_amdgcn_s_setprio(0);
    __syncthreads();
  }

  const int lr4 = (lane >> 4) * 4;
#pragma unroll
  for (int mt = 0; mt < 4; ++mt) {
#pragma unroll
    for (int nt = 0; nt < 4; ++nt) {
      const int col = col0 + cw + nt * 16 + lm;
      const float bv = HAS_BIAS ? bias[col] : 0.0f;
#pragma unroll
      for (int r = 0; r < 4; ++r) {
        const int row = row0 + rw + mt * 16 + lr4 + r;
        float v = acc[mt][nt][r] + bv;
        if (RELU) v = fmaxf(v, 0.0f);
        if (OUT_BF16)
          ((__hip_bfloat16*)Cg)[(long)z * strideC + (long)row * ldc + col] = __float2bfloat16(v);
        else
          ((float*)Cg)[(long)z * strideC + (long)row * ldc + col] = v;
      }
    }
  }
}

// ---------------------------------------------------------------------------
// 64x64-tile GEMM v2: double-buffered, one barrier per k-step (v7 pattern).
// ---------------------------------------------------------------------------
template<bool RELU, bool OUT_BF16, bool HAS_BIAS>
__global__ __launch_bounds__(256) void gemm_bt64(
    const __hip_bfloat16* __restrict__ Ag, const __hip_bfloat16* __restrict__ Bg,
    const float* __restrict__ biasg, void* __restrict__ Cg,
    int lda, int ldb, int K, int ldc,
    int strideA, int strideB, int strideBias, long strideC)
{
  __shared__ __align__(16) short As[2][2048];
  __shared__ __align__(16) short Bs[2][2048];
  const int tid  = threadIdx.x;
  const int lane = tid & 63;
  const int wid  = tid >> 6;
  const int z    = blockIdx.z;
  const __hip_bfloat16* A = Ag + (long)z * strideA;
  const __hip_bfloat16* B = Bg + (long)z * strideB;
  const float* bias = HAS_BIAS ? (biasg + (long)z * strideBias) : nullptr;
  const int row0 = blockIdx.y * 64;
  const int col0 = blockIdx.x * 64;

  const int srow = wid * 16 + (lane >> 2);
  const int scol = (lane & 3) * 8;

  f32x4 acc[2][2];
#pragma unroll
  for (int i = 0; i < 2; ++i)
#pragma unroll
    for (int j = 0; j < 2; ++j) acc[i][j] = (f32x4)(0.0f);

  const int rw = (wid & 1) * 32;
  const int cw = (wid >> 1) * 32;
  const int lm = lane & 15;
  const int kg = (lane >> 4) * 8;
  const int nk = K >> 5;

  // prologue: k-step 0 -> buffer 0
  async_lds16(A + (long)(row0 + srow) * lda + scol, (char*)As[0] + wid * 1024);
  async_lds16(B + (long)(col0 + srow) * ldb + scol, (char*)Bs[0] + wid * 1024);
  __syncthreads();

  for (int it = 0; it < nk; ++it) {
    const int cur = it & 1;
    if (it + 1 < nk) {
      const int ksn = (it + 1) << 5;
      async_lds16(A + (long)(row0 + srow) * lda + ksn + scol,
                  (char*)As[cur ^ 1] + wid * 1024);
      async_lds16(B + (long)(col0 + srow) * ldb + ksn + scol,
                  (char*)Bs[cur ^ 1] + wid * 1024);
    }
    s16x8 af[2], bf[2];
#pragma unroll
    for (int mt = 0; mt < 2; ++mt)
      af[mt] = *(const s16x8*)(As[cur] + (rw + mt * 16 + lm) * 32 + kg);
#pragma unroll
    for (int nt = 0; nt < 2; ++nt)
      bf[nt] = *(const s16x8*)(Bs[cur] + (cw + nt * 16 + lm) * 32 + kg);
    __builtin_amdgcn_s_setprio(1);
#pragma unroll
    for (int mt = 0; mt < 2; ++mt)
#pragma unroll
      for (int nt = 0; nt < 2; ++nt)
        acc[mt][nt] = __builtin_amdgcn_mfma_f32_16x16x32_bf16(af[mt], bf[nt], acc[mt][nt], 0, 0, 0);
    __builtin_amdgcn_s_setprio(0);
    __syncthreads();
  }

  const int lr4 = (lane >> 4) * 4;
#pragma unroll
  for (int mt = 0; mt < 2; ++mt) {
#pragma unroll
    for (int nt = 0; nt < 2; ++nt) {
      const int col = col0 + cw + nt * 16 + lm;
      const float bv = HAS_BIAS ? bias[col] : 0.0f;
#pragma unroll
      for (int r = 0; r < 4; ++r) {
        const int row = row0 + rw + mt * 16 + lr4 + r;
        float v = acc[mt][nt][r] + bv;
        if (RELU) v = fmaxf(v, 0.0f);
        if (OUT_BF16)
          ((__hip_bfloat16*)Cg)[(long)z * strideC + (long)row * ldc + col] = __float2bfloat16(v);
        else
          ((float*)Cg)[(long)z * strideC + (long)row * ldc + col] = v;
      }
    }
  }
}

// ---------------------------------------------------------------------------
// Split-K reduce for G1: H1 = relu(P0 + P1 + cboth) -> bf16. 4096x1024, 8-wide.
// ---------------------------------------------------------------------------
__global__ __launch_bounds__(256) void reduce_relu(
    const float* __restrict__ P, const float* __restrict__ cboth,
    __hip_bfloat16* __restrict__ H1)
{
  const int id = blockIdx.x * 256 + threadIdx.x;   // 524288 total
  const int row = id >> 7, c8 = id & 127;
  const f32x4* p0 = (const f32x4*)(P + (long)row * 1024 + c8 * 8);
  const f32x4* p1 = (const f32x4*)(P + 4194304 + (long)row * 1024 + c8 * 8);
  const f32x4* bb = (const f32x4*)(cboth + c8 * 8);
  f32x4 a = p0[0] + p1[0] + bb[0];
  f32x4 b = p0[1] + p1[1] + bb[1];
#pragma unroll
  for (int e = 0; e < 4; ++e) { a[e] = fmaxf(a[e], 0.0f); b[e] = fmaxf(b[e], 0.0f); }
  *(s16x8*)((short*)H1 + (long)row * 1024 + c8 * 8) = pack8(a, b);
}

// ---------------------------------------------------------------------------
// Fused relation head v7 (unchanged from R6): K=32 chunks, 4 blocks/CU,
// cooperative swizzled LDS-H formation, double-buffered Ws, 1 barrier/chunk.
// ---------------------------------------------------------------------------
__global__ __launch_bounds__(256, 4) void rel_final(
    const float* __restrict__ AsBo, const __hip_bfloat16* __restrict__ W2b,
    const float* __restrict__ b2, float* __restrict__ out)
{
  __shared__ __align__(16) short Ws[2][8192];   // 2 x 16 KB: [256 n][32 k]
  __shared__ __align__(16) short Hs[2][2048];   // 2 x 4 KB:  [64 j][32 k]
  const int tid  = threadIdx.x;
  const int lane = tid & 63;
  const int wid  = tid >> 6;
  // bijective XCD-chunk swizzle (4096 % 8 == 0): 8 consecutive t per XCD
  const int bid = (int)blockIdx.x;
  const int swz = (bid & 7) * 512 + (bid >> 3);
  const int t = swz >> 6;       // 0..63
  const int i = swz & 63;       // 0..63

  const float* Ap = AsBo + (long)(t * 64 + i) * 512;
  const float* Bp = AsBo + 2097152 + (long)t * 64 * 512;

  const int lm   = lane & 15;
  const int kgrp = lane >> 4;

  // formation mapping: thread -> (row fj 0..63, 8-wide k-slice fks 0..3)
  const int fj  = tid >> 2;
  const int fks = tid & 3;
  const float* fb = Bp + fj * 512 + fks * 8;
  const float* fa = Ap + fks * 8;
  // swizzled H write byte offset: physical slot = fks ^ ((fj>>1)&3)
  const int hw = fj * 64 + ((fks ^ ((fj >> 1) & 3)) << 4);

  // Ws staging: issue q fills rows wid*64 + q*16 + (lane>>2); lane writes
  // 16 B at physical slot lane&3; source supplies logical slot
  // (lane&3) ^ ((row>>1)&3) = (lane&3) ^ ((lane>>3)&3).
  const char* w2src = (const char*)W2b
      + (long)(wid * 64 + (lane >> 2)) * 1024
      + ((((lane & 3) ^ ((lane >> 3) & 3))) << 4);

  // fragment read slot: physical slot = kgrp ^ ((lm>>1)&3)
  const int fslot = (kgrp ^ ((lm >> 1) & 3)) << 4;

  f32x4 acc[4][4];
#pragma unroll
  for (int a = 0; a < 4; ++a)
#pragma unroll
    for (int b = 0; b < 4; ++b) acc[a][b] = (f32x4)(0.0f);

  // ---- prologue: chunk 0 -> buffer 0
  {
#pragma unroll
    for (int q = 0; q < 4; ++q)
      async_lds16(w2src + q * 16384, (char*)Ws[0] + wid * 4096 + q * 1024);
    f32x4 b0 = *(const f32x4*)(fb);
    f32x4 b1 = *(const f32x4*)(fb + 4);
    f32x4 a0 = *(const f32x4*)(fa);
    f32x4 a1 = *(const f32x4*)(fa + 4);
    f32x4 d0, d1;
#pragma unroll
    for (int e = 0; e < 4; ++e) {
      d0[e] = fmaxf(a0[e] - b0[e], 0.0f);
      d1[e] = fmaxf(a1[e] - b1[e], 0.0f);
    }
    *(s16x8*)((char*)Hs[0] + hw) = pack8(d0, d1);
  }
  __syncthreads();

#pragma unroll
  for (int ch = 0; ch < 16; ++ch) {
    const int cur = ch & 1;
    // fragment reads from current buffers (2-way bank aliasing = free)
    s16x8 af[4], bf[4];
#pragma unroll
    for (int mt = 0; mt < 4; ++mt)
      af[mt] = *(const s16x8*)((char*)Hs[cur] + (mt * 16 + lm) * 64 + fslot);
#pragma unroll
    for (int nt = 0; nt < 4; ++nt)
      bf[nt] = *(const s16x8*)((char*)Ws[cur] + wid * 4096 + nt * 1024
                               + lm * 64 + fslot);
    // issue next chunk's global work before MFMA (latency hides under compute)
    f32x4 av0, av1, bv0, bv1;
    if (ch < 15) {
      const int ko = (ch + 1) * 32;
      bv0 = *(const f32x4*)(fb + ko);
      bv1 = *(const f32x4*)(fb + ko + 4);
      av0 = *(const f32x4*)(fa + ko);
      av1 = *(const f32x4*)(fa + ko + 4);
#pragma unroll
      for (int q = 0; q < 4; ++q)
        async_lds16(w2src + (ch + 1) * 64 + q * 16384,
                    (char*)Ws[cur ^ 1] + wid * 4096 + q * 1024);
    }
    __builtin_amdgcn_s_setprio(1);
#pragma unroll
    for (int mt = 0; mt < 4; ++mt)
#pragma unroll
      for (int nt = 0; nt < 4; ++nt)
        acc[mt][nt] = __builtin_amdgcn_mfma_f32_16x16x32_bf16(
            af[mt], bf[nt], acc[mt][nt], 0, 0, 0);
    __builtin_amdgcn_s_setprio(0);
    if (ch < 15) {
      f32x4 d0, d1;
#pragma unroll
      for (int e = 0; e < 4; ++e) {
        d0[e] = fmaxf(av0[e] - bv0[e], 0.0f);
        d1[e] = fmaxf(av1[e] - bv1[e], 0.0f);
      }
      *(s16x8*)((char*)Hs[cur ^ 1] + hw) = pack8(d0, d1);
    }
    __syncthreads();
  }

  const long obase = (long)(t * 64 + i) * 16384;
#pragma unroll
  for (int mt = 0; mt < 4; ++mt) {
#pragma unroll
    for (int nt = 0; nt < 4; ++nt) {
      const int col = wid * 64 + nt * 16 + lm;
      const float bvv = b2[col];
#pragma unroll
      for (int r = 0; r < 4; ++r) {
        const int j = mt * 16 + kgrp * 4 + r;
        out[obase + j * 256 + col] = acc[mt][nt][r] + bvv;
      }
    }
  }
}

// ---------------------------------------------------------------------------
// Vectorized prep: 8-wide regions, float4 loads, s16x8 stores.
// ---------------------------------------------------------------------------
__global__ __launch_bounds__(256) void prep_kernel(
    const float* __restrict__ roi, const float* __restrict__ spatial,
    const float* __restrict__ subj_emb, const float* __restrict__ obj_emb,
    const float* __restrict__ pred_emb,
    const float* __restrict__ subj_w1, const float* __restrict__ subj_b1,
    const float* __restrict__ obj_w1, const float* __restrict__ obj_b1,
    const float* __restrict__ subj_w2, const float* __restrict__ subj_b2,
    const float* __restrict__ obj_w2, const float* __restrict__ obj_b2,
    const float* __restrict__ fs_w1, const float* __restrict__ fs_b1,
    const float* __restrict__ fs_w2, const float* __restrict__ fs_b2,
    const float* __restrict__ fo_w1, const float* __restrict__ fo_b1,
    const float* __restrict__ fo_w2, const float* __restrict__ fo_b2,
    const float* __restrict__ W_rs, const float* __restrict__ W_ro,
    const float* __restrict__ rel_w1, const float* __restrict__ rel_b1,
    const float* __restrict__ rel_w2,
    __hip_bfloat16* __restrict__ XP, __hip_bfloat16* __restrict__ W1P,
    float* __restrict__ cboth,
    __hip_bfloat16* __restrict__ Bcat2, float* __restrict__ bias2,
    __hip_bfloat16* __restrict__ WfCat, float* __restrict__ biasf,
    __hip_bfloat16* __restrict__ W4cat, float* __restrict__ bias4,
    __hip_bfloat16* __restrict__ WcCat, float* __restrict__ crel,
    __hip_bfloat16* __restrict__ W2b)
{
  int id = blockIdx.x * 256 + threadIdx.x;

  if (id < 1081344) {  // R1: XP 4096 x 2112
    int row = id / 264, c8 = id - row * 264;
    s16x8 o;
    if (c8 < 256) {
      const f32x4* src = (const f32x4*)(roi + (long)row * 2048 + c8 * 8);
      o = pack8(src[0], src[1]);
    } else {
      f32x4 a, b;
#pragma unroll
      for (int e = 0; e < 4; ++e) {
        int col = c8 * 8 + e;
        a[e] = (col < 2052) ? spatial[row * 4 + (col - 2048)] : 0.0f;
        int col2 = col + 4;
        b[e] = (col2 < 2052) ? spatial[row * 4 + (col2 - 2048)] : 0.0f;
      }
      o = pack8(a, b);
    }
    *(s16x8*)((short*)XP + (long)id * 8) = o;
    return;
  }
  id -= 1081344;
  if (id < 270336) {  // R2: W1P 1024 x 2112
    int row = id / 264, c8 = id - row * 264;
    const float* w = (row < 512) ? (subj_w1 + (long)row * 2352)
                                 : (obj_w1 + (long)(row - 512) * 2352);
    s16x8 o;
    if (c8 < 256) {
      const f32x4* src = (const f32x4*)(w + c8 * 8);
      o = pack8(src[0], src[1]);
    } else {
      f32x4 a, b;
#pragma unroll
      for (int e = 0; e < 4; ++e) {
        int col = c8 * 8 + e;
        a[e] = (col < 2052) ? w[col] : 0.0f;
        int col2 = col + 4;
        b[e] = (col2 < 2052) ? w[col2] : 0.0f;
      }
      o = pack8(a, b);
    }
    *(s16x8*)((short*)W1P + (long)id * 8) = o;
    return;
  }
  id -= 270336;
  if (id < 1024) {  // R3: cboth
    int h = id;
    const float* w; const float* e; float s;
    if (h < 512) { w = subj_w1 + (long)h * 2352 + 2052; e = subj_emb; s = subj_b1[h]; }
    else { w = obj_w1 + (long)(h - 512) * 2352 + 2052; e = obj_emb; s = obj_b1[h - 512]; }
    for (int k = 0; k < 300; ++k) s += w[k] * e[k];
    cboth[h] = s;
    return;
  }
  id -= 1024;
  if (id < 32768) {  // R4: Bcat2 copy-cast (units of 8)
    const float* src = (id < 16384) ? (subj_w2 + id * 8) : (obj_w2 + (id - 16384) * 8);
    const f32x4* s4 = (const f32x4*)src;
    *(s16x8*)((short*)Bcat2 + (long)id * 8) = pack8(s4[0], s4[1]);
    return;
  }
  id -= 32768;
  if (id < 512) { bias2[id] = (id < 256) ? subj_b2[id] : obj_b2[id - 256]; return; }
  id -= 512;
  if (id < 32768) {  // R6: WfCat = w1[:, :256] + w1[:, 256:]
    int z = id >> 14, r8 = id & 16383;
    int h = r8 >> 5, d8 = r8 & 31;
    const float* w = (z ? fo_w1 : fs_w1) + h * 512 + d8 * 8;
    const f32x4* lo = (const f32x4*)w;
    const f32x4* hi = (const f32x4*)(w + 256);
    *(s16x8*)((short*)WfCat + (long)id * 8) = pack8(lo[0] + hi[0], lo[1] + hi[1]);
    return;
  }
  id -= 32768;
  if (id < 1024) { biasf[id] = (id < 512) ? fs_b1[id] : fo_b1[id - 512]; return; }
  id -= 1024;
  if (id < 32768) {  // R8: W4cat copy-cast
    const float* src = (id < 16384) ? (fs_w2 + id * 8) : (fo_w2 + (id - 16384) * 8);
    const f32x4* s4 = (const f32x4*)src;
    *(s16x8*)((short*)W4cat + (long)id * 8) = pack8(s4[0], s4[1]);
    return;
  }
  id -= 32768;
  if (id < 512) { bias4[id] = (id < 256) ? fs_b2[id] : fo_b2[id - 256]; return; }
  id -= 512;
  if (id < 262144) {  // R10: WcCat[z][h][d] = sum_e rel_w1[h][e] * W_r{s,o}[e][d]
    int z = id >> 17, r = id & 131071;
    int h = r >> 8, d = r & 255;
    const float* Wr = z ? W_ro : W_rs;
    const float* wd = rel_w1 + (long)h * 556;
    float s = 0.0f;
    for (int e = 0; e < 256; ++e) s += wd[e] * Wr[e * 256 + d];
    WcCat[id] = __float2bfloat16(s);
    return;
  }
  id -= 262144;
  if (id < 1024) {  // R11: crel
    int z = id >> 9, h = id & 511;
    float s = 0.0f;
    if (z == 0) {
      s = rel_b1[h];
      const float* wp = rel_w1 + (long)h * 556 + 256;
      for (int k = 0; k < 300; ++k) s += pred_emb[k] * wp[k];
    }
    crel[id] = s;
    return;
  }
  id -= 1024;
  if (id < 16384) {  // R12: W2b copy-cast
    const f32x4* s4 = (const f32x4*)(rel_w2 + id * 8);
    *(s16x8*)((short*)W2b + (long)id * 8) = pack8(s4[0], s4[1]);
  }
}

extern "C" void kernel_launch(void* const* d_in, const int* in_sizes, int n_in,
                              void* d_out, int out_size, void* d_ws, size_t ws_size,
                              hipStream_t stream)
{
  const float* roi       = (const float*)d_in[0];
  const float* spatial   = (const float*)d_in[1];
  const float* subj_emb  = (const float*)d_in[3];
  const float* obj_emb   = (const float*)d_in[4];
  const float* pred_emb  = (const float*)d_in[5];
  const float* subj_w1   = (const float*)d_in[6];
  const float* subj_b1   = (const float*)d_in[7];
  const float* subj_w2   = (const float*)d_in[8];
  const float* subj_b2   = (const float*)d_in[9];
  const float* obj_w1    = (const float*)d_in[10];
  const float* obj_b1    = (const float*)d_in[11];
  const float* obj_w2    = (const float*)d_in[12];
  const float* obj_b2    = (const float*)d_in[13];
  const float* fuse_s_w1 = (const float*)d_in[14];
  const float* fuse_s_b1 = (const float*)d_in[15];
  const float* fuse_s_w2 = (const float*)d_in[16];
  const float* fuse_s_b2 = (const float*)d_in[17];
  const float* fuse_o_w1 = (const float*)d_in[18];
  const float* fuse_o_b1 = (const float*)d_in[19];
  const float* fuse_o_w2 = (const float*)d_in[20];
  const float* fuse_o_b2 = (const float*)d_in[21];
  const float* W_rs      = (const float*)d_in[22];
  const float* W_ro      = (const float*)d_in[23];
  const float* rel_w1    = (const float*)d_in[24];
  const float* rel_b1    = (const float*)d_in[25];
  const float* rel_w2    = (const float*)d_in[26];
  const float* rel_b2    = (const float*)d_in[27];

  char* ws = (char*)d_ws;
  // XP: 4096x2112 bf16 = 17,301,504 B ; later reused as AsBo (16,777,216 B fp32)
  __hip_bfloat16* XP   = (__hip_bfloat16*)(ws);
  float*          AsBo = (float*)(ws);
  __hip_bfloat16* W1P  = (__hip_bfloat16*)(ws + 17301504);   // 1024x2112 bf16 = 4,325,376
  __hip_bfloat16* H1   = (__hip_bfloat16*)(ws + 21626880);   // 4096x1024 bf16 = 8,388,608
  __hip_bfloat16* FS   = (__hip_bfloat16*)(ws + 30015488);   // 4096x512  bf16 = 4,194,304
  float*          P    = (float*)(ws + 34209792);            // 2x4096x1024 fp32 = 33,554,432
  const size_t so = 67764224;
  __hip_bfloat16* Bcat2 = (__hip_bfloat16*)(ws + so);
  float*          bias2 = (float*)(ws + so + 524288);
  __hip_bfloat16* WfCat = (__hip_bfloat16*)(ws + so + 526336);
  float*          biasf = (float*)(ws + so + 1050624);
  __hip_bfloat16* W4cat = (__hip_bfloat16*)(ws + so + 1054720);
  float*          bias4 = (float*)(ws + so + 1579008);
  __hip_bfloat16* WcCat = (__hip_bfloat16*)(ws + so + 1581056);
  float*          crel  = (float*)(ws + so + 2105344);
  __hip_bfloat16* W2b   = (__hip_bfloat16*)(ws + so + 2109440);
  float*          cboth = (float*)(ws + so + 2371584);
  // total ws use ~70.2 MB

  prep_kernel<<<6768, 256, 0, stream>>>(
      roi, spatial, subj_emb, obj_emb, pred_emb,
      subj_w1, subj_b1, obj_w1, obj_b1, subj_w2, subj_b2, obj_w2, obj_b2,
      fuse_s_w1, fuse_s_b1, fuse_s_w2, fuse_s_b2,
      fuse_o_w1, fuse_o_b1, fuse_o_w2, fuse_o_b2,
      W_rs, W_ro, rel_w1, rel_b1, rel_w2,
      XP, W1P, cboth, Bcat2, bias2, WfCat, biasf, W4cat, bias4, WcCat, crel, W2b);

  // G1 split-K=2: P[z] = XP[:, z*1056:(z+1)*1056] @ W1P[:, same]^T  (fp32, no bias)
  gemm_bt<false, false, false><<<dim3(8, 32, 2), 256, 0, stream>>>(
      XP, W1P, cboth, P, 2112, 2112, 1056, 1024, 1056, 1056, 0, 4194304L);
  // reduce: H1 = relu(P0 + P1 + cboth) -> bf16
  reduce_relu<<<2048, 256, 0, stream>>>(P, cboth, H1);
  // G2: FS[:, z*256:] = H1[:, z*512:] @ w2_z^T + b2_z   K=512
  gemm_bt64<false, true, true><<<dim3(4, 64, 2), 256, 0, stream>>>(
      H1, Bcat2, bias2, FS, 1024, 512, 512, 512, 512, 131072, 256, 256);
  // G3: G[:, z*512:] = relu(FS[:, z*256:] @ Wf_z^T + bf_z)   K=256 (G in H1 slot)
  gemm_bt64<true, true, true><<<dim3(8, 64, 2), 256, 0, stream>>>(
      FS, WfCat, biasf, H1, 512, 256, 256, 1024, 256, 131072, 512, 512);
  // G4: Ffin[:, z*256:] = G[:, z*512:] @ w4_z^T + b4_z   K=512 (Ffin in FS slot)
  gemm_bt64<false, true, true><<<dim3(4, 64, 2), 256, 0, stream>>>(
      H1, W4cat, bias4, FS, 1024, 512, 512, 512, 512, 131072, 256, 256);
  // G5: AsBo[z] = Ffin[:, z*256:] @ Wc_z^T + crel_z  (fp32 out)  K=256
  gemm_bt64<false, false, true><<<dim3(8, 64, 2), 256, 0, stream>>>(
      FS, WcCat, crel, AsBo, 512, 256, 256, 512, 256, 131072, 512, 2097152L);
  // Fused relation head v7: K=32 chunks, 4 blocks/CU
  rel_final<<<4096, 256, 0, stream>>>(AsBo, W2b, rel_b2, (float*)d_out);
}